// Round 1
// baseline (1314.333 us; speedup 1.0000x reference)
//
#include <hip/hip_runtime.h>
#include <math.h>

#define B 8
#define Cc 256
#define P 4096     // 64*64 pixels
#define NW 64      // windows
#define T 64       // tokens per window
#define NH 8
#define HD 32
#define TOPK 4

// ---------------------------------------------------------------------------
// 1) window descriptors: mean over each 8x8 window, layout [b][c][n]
// ---------------------------------------------------------------------------
__global__ __launch_bounds__(256) void desc_kernel(
    const float* __restrict__ x, const float* __restrict__ p,
    float* __restrict__ dx, float* __restrict__ dp) {
  int wid = (blockIdx.x * 256 + threadIdx.x) >> 6;  // global wave id, 0..4095
  int lane = threadIdx.x & 63;
  int sel = wid >> 11;          // 0: x, 1: prompt
  int bc = wid & 2047;          // b*256 + c
  const float* img = (sel ? p : x) + (size_t)bc * P;
  float* d = (sel ? dp : dx) + (size_t)bc * NW;
  for (int wy = 0; wy < 8; ++wy) {
    float s = 0.f;
#pragma unroll
    for (int ty = 0; ty < 8; ++ty)
      s += img[(wy * 8 + ty) * 64 + lane];
    s += __shfl_xor(s, 1);
    s += __shfl_xor(s, 2);
    s += __shfl_xor(s, 4);
    if ((lane & 7) == 0)
      d[wy * 8 + (lane >> 3)] = s * (1.f / 64.f);
  }
}

// ---------------------------------------------------------------------------
// 2) routing scores + top-4 (desc dot / 16), jax top_k tie-break (lower idx)
// ---------------------------------------------------------------------------
__global__ __launch_bounds__(64) void route_kernel(
    const float* __restrict__ dx, const float* __restrict__ dp,
    int* __restrict__ routed) {
  int bq = blockIdx.x;          // b*64 + q
  int b = bq >> 6;
  int q = bq & 63;
  int lane = threadIdx.x;       // prompt window index
  const float* dxb = dx + (size_t)b * Cc * NW;
  const float* dpb = dp + (size_t)b * Cc * NW;
  float s = 0.f;
  for (int c = 0; c < Cc; ++c)
    s = fmaf(dxb[c * NW + q], dpb[c * NW + lane], s);
  s *= (1.f / 16.f);
  for (int kk = 0; kk < TOPK; ++kk) {
    float v = s;
    int i = lane;
    for (int off = 32; off; off >>= 1) {
      float ov = __shfl_xor(v, off);
      int oi = __shfl_xor(i, off);
      if (ov > v || (ov == v && oi < i)) { v = ov; i = oi; }
    }
    if (lane == 0) routed[bq * TOPK + kk] = i;
    if (lane == i) s = -INFINITY;
  }
}

// ---------------------------------------------------------------------------
// 3) conv1x1 GEMM: Out[b,o,p] = sum_k W[o,k] * A[b,k,p]
//    A split across two pointers (for gate: k<K1 -> A1 (=x), else A2 (=y))
//    tile 64(o) x 64(p), BK=16, 256 threads, 4x4 per thread
// ---------------------------------------------------------------------------
#define BK 16
__global__ __launch_bounds__(256) void conv1x1_kernel(
    const float* __restrict__ A1, const float* __restrict__ A2,
    const float* __restrict__ Wmat, float* __restrict__ Out,
    int K1, int Ktot) {
  __shared__ float As[BK][68];
  __shared__ float Ws[64][20];
  int pb = blockIdx.x * 64;
  int ob = blockIdx.y * 64;
  int b = blockIdx.z;
  int tid = threadIdx.x;
  int tx = tid & 15, ty = tid >> 4;
  const float* A1b = A1 + (size_t)b * Cc * P;
  const float* A2b = A2 ? (A2 + (size_t)b * Cc * P) : nullptr;
  float acc[4][4] = {};
  for (int k0 = 0; k0 < Ktot; k0 += BK) {
    {
      int r = tid >> 4;              // k row 0..15
      int cst = (tid & 15) * 4;      // p col
      const float* src = (k0 + r < K1)
          ? (A1b + (size_t)(k0 + r) * P + pb + cst)
          : (A2b + (size_t)(k0 + r - K1) * P + pb + cst);
      float4 v = *reinterpret_cast<const float4*>(src);
      As[r][cst] = v.x; As[r][cst + 1] = v.y;
      As[r][cst + 2] = v.z; As[r][cst + 3] = v.w;
    }
    {
      int o = tid >> 2;
      int kc = (tid & 3) * 4;
      float4 v = *reinterpret_cast<const float4*>(
          Wmat + (size_t)(ob + o) * Ktot + k0 + kc);
      Ws[o][kc] = v.x; Ws[o][kc + 1] = v.y;
      Ws[o][kc + 2] = v.z; Ws[o][kc + 3] = v.w;
    }
    __syncthreads();
#pragma unroll
    for (int kc = 0; kc < BK; kc += 4) {
      float w_[4][4], a_[4][4];
#pragma unroll
      for (int oo = 0; oo < 4; ++oo) {
        float4 wv = *reinterpret_cast<const float4*>(&Ws[ty * 4 + oo][kc]);
        w_[0][oo] = wv.x; w_[1][oo] = wv.y; w_[2][oo] = wv.z; w_[3][oo] = wv.w;
      }
#pragma unroll
      for (int j = 0; j < 4; ++j) {
        float4 av = *reinterpret_cast<const float4*>(&As[kc + j][tx * 4]);
        a_[j][0] = av.x; a_[j][1] = av.y; a_[j][2] = av.z; a_[j][3] = av.w;
      }
#pragma unroll
      for (int j = 0; j < 4; ++j)
#pragma unroll
        for (int oo = 0; oo < 4; ++oo)
#pragma unroll
          for (int pp = 0; pp < 4; ++pp)
            acc[oo][pp] = fmaf(w_[j][oo], a_[j][pp], acc[oo][pp]);
    }
    __syncthreads();
  }
  float* Ob = Out + (size_t)b * Cc * P;
#pragma unroll
  for (int oo = 0; oo < 4; ++oo) {
    float4 v = make_float4(acc[oo][0], acc[oo][1], acc[oo][2], acc[oo][3]);
    *reinterpret_cast<float4*>(Ob + (size_t)(ob + ty * 4 + oo) * P + pb + tx * 4) = v;
  }
}

// ---------------------------------------------------------------------------
// 4) attention: one wave per (b, window, head); lane = query token.
//    no-max softmax (logits ~N(0,1), f32 exp safe); K/V reads are
//    wave-uniform -> scalar loads.
// ---------------------------------------------------------------------------
__global__ __launch_bounds__(64) void attn_kernel(
    const float* __restrict__ Q, const float* __restrict__ K,
    const float* __restrict__ V, const int* __restrict__ routed,
    float* __restrict__ O) {
  int id = blockIdx.x;            // ((b*NW + n)*NH + h)
  int h = id & 7;
  int n = (id >> 3) & 63;
  int b = id >> 9;
  int t = threadIdx.x;
  int wy = n >> 3, wx = n & 7;
  int pt = (wy * 8 + (t >> 3)) * 64 + wx * 8 + (t & 7);
  const float* Qb = Q + ((size_t)(b * Cc) + h * HD) * P + pt;
  float q[HD];
#pragma unroll
  for (int d = 0; d < HD; ++d) q[d] = Qb[(size_t)d * P];
  float l = 0.f;
  float acc[HD] = {};
  const float* Kb0 = K + ((size_t)(b * Cc) + h * HD) * P;
  const float* Vb0 = V + ((size_t)(b * Cc) + h * HD) * P;
  const int* rptr = routed + (b * NW + n) * TOPK;
  for (int kk = 0; kk < TOPK; ++kk) {
    int pw = __builtin_amdgcn_readfirstlane(rptr[kk]);
    int py0 = (pw >> 3) * 8, px0 = (pw & 7) * 8;
    for (int jt = 0; jt < T; ++jt) {
      int pj = (py0 + (jt >> 3)) * 64 + px0 + (jt & 7);
      const float* Kb = Kb0 + pj;
      float s = 0.f;
#pragma unroll
      for (int d = 0; d < HD; ++d) s = fmaf(q[d], Kb[(size_t)d * P], s);
      float pe = __expf(s * 0.17677669529663687f);
      l += pe;
      const float* Vb = Vb0 + pj;
#pragma unroll
      for (int d = 0; d < HD; ++d) acc[d] = fmaf(pe, Vb[(size_t)d * P], acc[d]);
    }
  }
  float inv = 1.f / l;
  float* Ob = O + ((size_t)(b * Cc) + h * HD) * P + pt;
#pragma unroll
  for (int d = 0; d < HD; ++d) Ob[(size_t)d * P] = acc[d] * inv;
}

// ---------------------------------------------------------------------------
// 5) batch-norm stats per channel (biased var) -> scale/shift
// ---------------------------------------------------------------------------
__global__ __launch_bounds__(256) void bnstat_kernel(
    const float* __restrict__ G, const float* __restrict__ gamma,
    const float* __restrict__ beta, float* __restrict__ scale,
    float* __restrict__ shift) {
  int o = blockIdx.x;
  int tid = threadIdx.x;
  float s = 0.f, ss = 0.f;
  for (int b = 0; b < B; ++b) {
    const float* g = G + ((size_t)b * Cc + o) * P;
    for (int p = tid; p < P; p += 256) {
      float v = g[p];
      s += v;
      ss = fmaf(v, v, ss);
    }
  }
  for (int off = 32; off; off >>= 1) {
    s += __shfl_xor(s, off);
    ss += __shfl_xor(ss, off);
  }
  __shared__ float bs[4], bss[4];
  int wv = tid >> 6;
  if ((tid & 63) == 0) { bs[wv] = s; bss[wv] = ss; }
  __syncthreads();
  if (tid == 0) {
    float S = bs[0] + bs[1] + bs[2] + bs[3];
    float SS = bss[0] + bss[1] + bss[2] + bss[3];
    const float N = (float)(B * P);
    float mean = S / N;
    float var = SS / N - mean * mean;
    float rstd = rsqrtf(var + 1e-5f);
    float sc = rstd * gamma[o];
    scale[o] = sc;
    shift[o] = beta[o] - mean * sc;
  }
}

// ---------------------------------------------------------------------------
// 6) out = x + sigmoid(g*scale + shift) * y
// ---------------------------------------------------------------------------
__global__ __launch_bounds__(256) void final_kernel(
    const float* __restrict__ x, const float* __restrict__ Y,
    const float* __restrict__ G, const float* __restrict__ scale,
    const float* __restrict__ shift, float* __restrict__ out) {
  int bc = blockIdx.y;            // b*256 + c
  int c = bc & 255;
  size_t base = (size_t)bc * P + blockIdx.x * 1024 + threadIdx.x * 4;
  float sc = scale[c], sh = shift[c];
  float4 xv = *reinterpret_cast<const float4*>(x + base);
  float4 yv = *reinterpret_cast<const float4*>(Y + base);
  float4 gv = *reinterpret_cast<const float4*>(G + base);
  float4 o;
  o.x = xv.x + yv.x / (1.f + __expf(-(fmaf(gv.x, sc, sh))));
  o.y = xv.y + yv.y / (1.f + __expf(-(fmaf(gv.y, sc, sh))));
  o.z = xv.z + yv.z / (1.f + __expf(-(fmaf(gv.z, sc, sh))));
  o.w = xv.w + yv.w / (1.f + __expf(-(fmaf(gv.w, sc, sh))));
  *reinterpret_cast<float4*>(out + base) = o;
}

// ---------------------------------------------------------------------------
extern "C" void kernel_launch(void* const* d_in, const int* in_sizes, int n_in,
                              void* d_out, int out_size, void* d_ws, size_t ws_size,
                              hipStream_t stream) {
  const float* x      = (const float*)d_in[0];
  const float* prompt = (const float*)d_in[1];
  const float* Wq     = (const float*)d_in[2];
  const float* Wk     = (const float*)d_in[3];
  const float* Wv     = (const float*)d_in[4];
  const float* Wproj  = (const float*)d_in[5];
  const float* Wg     = (const float*)d_in[6];
  const float* gamma  = (const float*)d_in[7];
  const float* beta   = (const float*)d_in[8];

  float* ws = (float*)d_ws;
  const size_t IMG = (size_t)B * Cc * P;   // 8,388,608
  float* Qb = ws;
  float* Kb = ws + IMG;
  float* Vb = ws + 2 * IMG;
  float* Ob = ws + 3 * IMG;
  float* dx = ws + 4 * IMG;
  float* dp = dx + (size_t)B * Cc * NW;
  float* scale = dp + (size_t)B * Cc * NW;
  float* shift = scale + 256;
  int* routed = (int*)(shift + 256);
  float* Yb = Qb;   // reuse: Q dead after attention
  float* Gb = Kb;   // reuse: K dead after attention

  desc_kernel<<<1024, 256, 0, stream>>>(x, prompt, dx, dp);
  route_kernel<<<B * NW, 64, 0, stream>>>(dx, dp, routed);
  conv1x1_kernel<<<dim3(P / 64, Cc / 64, B), 256, 0, stream>>>(x, nullptr, Wq, Qb, 256, 256);
  conv1x1_kernel<<<dim3(P / 64, Cc / 64, B), 256, 0, stream>>>(prompt, nullptr, Wk, Kb, 256, 256);
  conv1x1_kernel<<<dim3(P / 64, Cc / 64, B), 256, 0, stream>>>(prompt, nullptr, Wv, Vb, 256, 256);
  attn_kernel<<<B * NW * NH, 64, 0, stream>>>(Qb, Kb, Vb, routed, Ob);
  conv1x1_kernel<<<dim3(P / 64, Cc / 64, B), 256, 0, stream>>>(Ob, nullptr, Wproj, Yb, 256, 256);
  conv1x1_kernel<<<dim3(P / 64, Cc / 64, B), 256, 0, stream>>>(x, Yb, Wg, Gb, 256, 512);
  bnstat_kernel<<<256, 256, 0, stream>>>(Gb, gamma, beta, scale, shift);
  final_kernel<<<dim3(4, B * Cc), 256, 0, stream>>>(x, Yb, Gb, scale, shift, (float*)d_out);
}

// Round 2
// 944.831 us; speedup vs baseline: 1.3911x; 1.3911x over previous
//
#include <hip/hip_runtime.h>
#include <math.h>

#define B 8
#define Cc 256
#define P 4096     // 64*64 pixels
#define NW 64      // windows
#define T 64       // tokens per window
#define NH 8
#define HD 32
#define TOPK 4

// ---------------------------------------------------------------------------
// 1) window descriptors: mean over each 8x8 window, layout [b][c][n]
// ---------------------------------------------------------------------------
__global__ __launch_bounds__(256) void desc_kernel(
    const float* __restrict__ x, const float* __restrict__ p,
    float* __restrict__ dx, float* __restrict__ dp) {
  int wid = (blockIdx.x * 256 + threadIdx.x) >> 6;  // global wave id, 0..4095
  int lane = threadIdx.x & 63;
  int sel = wid >> 11;          // 0: x, 1: prompt
  int bc = wid & 2047;          // b*256 + c
  const float* img = (sel ? p : x) + (size_t)bc * P;
  float* d = (sel ? dp : dx) + (size_t)bc * NW;
  for (int wy = 0; wy < 8; ++wy) {
    float s = 0.f;
#pragma unroll
    for (int ty = 0; ty < 8; ++ty)
      s += img[(wy * 8 + ty) * 64 + lane];
    s += __shfl_xor(s, 1);
    s += __shfl_xor(s, 2);
    s += __shfl_xor(s, 4);
    if ((lane & 7) == 0)
      d[wy * 8 + (lane >> 3)] = s * (1.f / 64.f);
  }
}

// ---------------------------------------------------------------------------
// 2) routing scores + top-4 (desc dot / 16), jax top_k tie-break (lower idx)
// ---------------------------------------------------------------------------
__global__ __launch_bounds__(64) void route_kernel(
    const float* __restrict__ dx, const float* __restrict__ dp,
    int* __restrict__ routed) {
  int bq = blockIdx.x;          // b*64 + q
  int b = bq >> 6;
  int q = bq & 63;
  int lane = threadIdx.x;       // prompt window index
  const float* dxb = dx + (size_t)b * Cc * NW;
  const float* dpb = dp + (size_t)b * Cc * NW;
  float s = 0.f;
  for (int c = 0; c < Cc; ++c)
    s = fmaf(dxb[c * NW + q], dpb[c * NW + lane], s);
  s *= (1.f / 16.f);
  for (int kk = 0; kk < TOPK; ++kk) {
    float v = s;
    int i = lane;
    for (int off = 32; off; off >>= 1) {
      float ov = __shfl_xor(v, off);
      int oi = __shfl_xor(i, off);
      if (ov > v || (ov == v && oi < i)) { v = ov; i = oi; }
    }
    if (lane == 0) routed[bq * TOPK + kk] = i;
    if (lane == i) s = -INFINITY;
  }
}

// ---------------------------------------------------------------------------
// 3) conv1x1 GEMM: Out[b,o,p] = sum_k W[o,k] * A[b,k,p]
//    A split across two pointers (for gate: k<K1 -> A1 (=x), else A2 (=y))
//    tile 64(o) x 64(p), BK=16, 256 threads, 4x4 per thread.
//    windowed=1: store to [b][n][h][t][hd] (for K/V feeding attention)
// ---------------------------------------------------------------------------
#define BK 16
__global__ __launch_bounds__(256) void conv1x1_kernel(
    const float* __restrict__ A1, const float* __restrict__ A2,
    const float* __restrict__ Wmat, float* __restrict__ Out,
    int K1, int Ktot, int windowed) {
  __shared__ float As[BK][68];
  __shared__ float Ws[64][20];
  int pb = blockIdx.x * 64;
  int ob = blockIdx.y * 64;
  int b = blockIdx.z;
  int tid = threadIdx.x;
  int tx = tid & 15, ty = tid >> 4;
  const float* A1b = A1 + (size_t)b * Cc * P;
  const float* A2b = A2 ? (A2 + (size_t)b * Cc * P) : nullptr;
  float acc[4][4] = {};
  for (int k0 = 0; k0 < Ktot; k0 += BK) {
    {
      int r = tid >> 4;              // k row 0..15
      int cst = (tid & 15) * 4;      // p col
      const float* src = (k0 + r < K1)
          ? (A1b + (size_t)(k0 + r) * P + pb + cst)
          : (A2b + (size_t)(k0 + r - K1) * P + pb + cst);
      float4 v = *reinterpret_cast<const float4*>(src);
      As[r][cst] = v.x; As[r][cst + 1] = v.y;
      As[r][cst + 2] = v.z; As[r][cst + 3] = v.w;
    }
    {
      int o = tid >> 2;
      int kc = (tid & 3) * 4;
      float4 v = *reinterpret_cast<const float4*>(
          Wmat + (size_t)(ob + o) * Ktot + k0 + kc);
      Ws[o][kc] = v.x; Ws[o][kc + 1] = v.y;
      Ws[o][kc + 2] = v.z; Ws[o][kc + 3] = v.w;
    }
    __syncthreads();
#pragma unroll
    for (int kc = 0; kc < BK; kc += 4) {
      float w_[4][4], a_[4][4];
#pragma unroll
      for (int oo = 0; oo < 4; ++oo) {
        float4 wv = *reinterpret_cast<const float4*>(&Ws[ty * 4 + oo][kc]);
        w_[0][oo] = wv.x; w_[1][oo] = wv.y; w_[2][oo] = wv.z; w_[3][oo] = wv.w;
      }
#pragma unroll
      for (int j = 0; j < 4; ++j) {
        float4 av = *reinterpret_cast<const float4*>(&As[kc + j][tx * 4]);
        a_[j][0] = av.x; a_[j][1] = av.y; a_[j][2] = av.z; a_[j][3] = av.w;
      }
#pragma unroll
      for (int j = 0; j < 4; ++j)
#pragma unroll
        for (int oo = 0; oo < 4; ++oo)
#pragma unroll
          for (int pp = 0; pp < 4; ++pp)
            acc[oo][pp] = fmaf(w_[j][oo], a_[j][pp], acc[oo][pp]);
    }
    __syncthreads();
  }
  if (!windowed) {
    float* Ob = Out + (size_t)b * Cc * P;
#pragma unroll
    for (int oo = 0; oo < 4; ++oo) {
      float4 v = make_float4(acc[oo][0], acc[oo][1], acc[oo][2], acc[oo][3]);
      *reinterpret_cast<float4*>(Ob + (size_t)(ob + ty * 4 + oo) * P + pb + tx * 4) = v;
    }
  } else {
    // windowed store: dst[((b*NW+n)*NH+h)*T*HD + t*HD + d], float4 along d
    int hh = (ob + ty * 4) >> 5;
    int dd = (ob + ty * 4) & 31;
#pragma unroll
    for (int pp = 0; pp < 4; ++pp) {
      int p = pb + tx * 4 + pp;
      int pyr = p >> 6, px = p & 63;
      int n = ((pyr >> 3) << 3) + (px >> 3);
      int t = ((pyr & 7) << 3) + (px & 7);
      float4 v = make_float4(acc[0][pp], acc[1][pp], acc[2][pp], acc[3][pp]);
      *reinterpret_cast<float4*>(
          Out + ((((size_t)b * NW + n) * NH + hh) * T + t) * HD + dd) = v;
    }
  }
}

// ---------------------------------------------------------------------------
// 4) attention v2: block = (b, window), 8 waves = 8 heads, lane = query token.
//    K/V in windowed layout [b][n][h][t][hd] -> contiguous 128B per token,
//    wave-uniform broadcast float4 loads. Q read from image layout (one-time).
// ---------------------------------------------------------------------------
__global__ __launch_bounds__(512) void attn_kernel(
    const float* __restrict__ Q, const float* __restrict__ Kw,
    const float* __restrict__ Vw, const int* __restrict__ routed,
    float* __restrict__ O) {
  int bn = blockIdx.x;            // b*NW + n
  int b = bn >> 6;
  int n = bn & 63;
  int h = threadIdx.x >> 6;       // wave = head
  int t = threadIdx.x & 63;
  int wy = n >> 3, wx = n & 7;
  int pt = (wy * 8 + (t >> 3)) * 64 + wx * 8 + (t & 7);
  const float* Qb = Q + ((size_t)(b * Cc) + h * HD) * P + pt;
  float q[HD];
#pragma unroll
  for (int d = 0; d < HD; ++d) q[d] = Qb[(size_t)d * P];
  float l = 0.f;
  float acc[HD] = {};
  const int* rptr = routed + bn * TOPK;
  for (int kk = 0; kk < TOPK; ++kk) {
    int pw = __builtin_amdgcn_readfirstlane(rptr[kk]);
    const float* Kp = Kw + (((size_t)(b * NW + pw)) * NH + h) * T * HD;
    const float* Vp = Vw + (((size_t)(b * NW + pw)) * NH + h) * T * HD;
#pragma unroll 2
    for (int j = 0; j < T; ++j) {
      const float4* k4 = reinterpret_cast<const float4*>(Kp + j * HD);
      float s = 0.f;
#pragma unroll
      for (int d4 = 0; d4 < 8; ++d4) {
        float4 kv = k4[d4];
        s = fmaf(q[d4 * 4 + 0], kv.x, s);
        s = fmaf(q[d4 * 4 + 1], kv.y, s);
        s = fmaf(q[d4 * 4 + 2], kv.z, s);
        s = fmaf(q[d4 * 4 + 3], kv.w, s);
      }
      float pe = __expf(s * 0.17677669529663687f);
      l += pe;
      const float4* v4 = reinterpret_cast<const float4*>(Vp + j * HD);
#pragma unroll
      for (int d4 = 0; d4 < 8; ++d4) {
        float4 vv = v4[d4];
        acc[d4 * 4 + 0] = fmaf(pe, vv.x, acc[d4 * 4 + 0]);
        acc[d4 * 4 + 1] = fmaf(pe, vv.y, acc[d4 * 4 + 1]);
        acc[d4 * 4 + 2] = fmaf(pe, vv.z, acc[d4 * 4 + 2]);
        acc[d4 * 4 + 3] = fmaf(pe, vv.w, acc[d4 * 4 + 3]);
      }
    }
  }
  float inv = 1.f / l;
  float* Ob = O + ((size_t)(b * Cc) + h * HD) * P + pt;
#pragma unroll
  for (int d = 0; d < HD; ++d) Ob[(size_t)d * P] = acc[d] * inv;
}

// ---------------------------------------------------------------------------
// 5) batch-norm stats per channel (biased var) -> scale/shift
// ---------------------------------------------------------------------------
__global__ __launch_bounds__(256) void bnstat_kernel(
    const float* __restrict__ G, const float* __restrict__ gamma,
    const float* __restrict__ beta, float* __restrict__ scale,
    float* __restrict__ shift) {
  int o = blockIdx.x;
  int tid = threadIdx.x;
  float s = 0.f, ss = 0.f;
  for (int b = 0; b < B; ++b) {
    const float* g = G + ((size_t)b * Cc + o) * P;
    for (int p = tid; p < P; p += 256) {
      float v = g[p];
      s += v;
      ss = fmaf(v, v, ss);
    }
  }
  for (int off = 32; off; off >>= 1) {
    s += __shfl_xor(s, off);
    ss += __shfl_xor(ss, off);
  }
  __shared__ float bs[4], bss[4];
  int wv = tid >> 6;
  if ((tid & 63) == 0) { bs[wv] = s; bss[wv] = ss; }
  __syncthreads();
  if (tid == 0) {
    float S = bs[0] + bs[1] + bs[2] + bs[3];
    float SS = bss[0] + bss[1] + bss[2] + bss[3];
    const float N = (float)(B * P);
    float mean = S / N;
    float var = SS / N - mean * mean;
    float rstd = rsqrtf(var + 1e-5f);
    float sc = rstd * gamma[o];
    scale[o] = sc;
    shift[o] = beta[o] - mean * sc;
  }
}

// ---------------------------------------------------------------------------
// 6) out = x + sigmoid(g*scale + shift) * y
// ---------------------------------------------------------------------------
__global__ __launch_bounds__(256) void final_kernel(
    const float* __restrict__ x, const float* __restrict__ Y,
    const float* __restrict__ G, const float* __restrict__ scale,
    const float* __restrict__ shift, float* __restrict__ out) {
  int bc = blockIdx.y;            // b*256 + c
  int c = bc & 255;
  size_t base = (size_t)bc * P + blockIdx.x * 1024 + threadIdx.x * 4;
  float sc = scale[c], sh = shift[c];
  float4 xv = *reinterpret_cast<const float4*>(x + base);
  float4 yv = *reinterpret_cast<const float4*>(Y + base);
  float4 gv = *reinterpret_cast<const float4*>(G + base);
  float4 o;
  o.x = xv.x + yv.x / (1.f + __expf(-(fmaf(gv.x, sc, sh))));
  o.y = xv.y + yv.y / (1.f + __expf(-(fmaf(gv.y, sc, sh))));
  o.z = xv.z + yv.z / (1.f + __expf(-(fmaf(gv.z, sc, sh))));
  o.w = xv.w + yv.w / (1.f + __expf(-(fmaf(gv.w, sc, sh))));
  *reinterpret_cast<float4*>(out + base) = o;
}

// ---------------------------------------------------------------------------
extern "C" void kernel_launch(void* const* d_in, const int* in_sizes, int n_in,
                              void* d_out, int out_size, void* d_ws, size_t ws_size,
                              hipStream_t stream) {
  const float* x      = (const float*)d_in[0];
  const float* prompt = (const float*)d_in[1];
  const float* Wq     = (const float*)d_in[2];
  const float* Wk     = (const float*)d_in[3];
  const float* Wv     = (const float*)d_in[4];
  const float* Wproj  = (const float*)d_in[5];
  const float* Wg     = (const float*)d_in[6];
  const float* gamma  = (const float*)d_in[7];
  const float* beta   = (const float*)d_in[8];

  float* ws = (float*)d_ws;
  const size_t IMG = (size_t)B * Cc * P;   // 8,388,608
  float* Qb = ws;                 // image layout
  float* Kw = ws + IMG;           // windowed layout [b][n][h][t][hd]
  float* Vw = ws + 2 * IMG;       // windowed layout
  float* Ob = ws + 3 * IMG;       // image layout
  float* dx = ws + 4 * IMG;
  float* dp = dx + (size_t)B * Cc * NW;
  float* scale = dp + (size_t)B * Cc * NW;
  float* shift = scale + 256;
  int* routed = (int*)(shift + 256);
  float* Yb = Qb;   // reuse: Q dead after attention
  float* Gb = Kw;   // reuse: Kw dead after attention

  desc_kernel<<<1024, 256, 0, stream>>>(x, prompt, dx, dp);
  route_kernel<<<B * NW, 64, 0, stream>>>(dx, dp, routed);
  conv1x1_kernel<<<dim3(P / 64, Cc / 64, B), 256, 0, stream>>>(x, nullptr, Wq, Qb, 256, 256, 0);
  conv1x1_kernel<<<dim3(P / 64, Cc / 64, B), 256, 0, stream>>>(prompt, nullptr, Wk, Kw, 256, 256, 1);
  conv1x1_kernel<<<dim3(P / 64, Cc / 64, B), 256, 0, stream>>>(prompt, nullptr, Wv, Vw, 256, 256, 1);
  attn_kernel<<<B * NW, 512, 0, stream>>>(Qb, Kw, Vw, routed, Ob);
  conv1x1_kernel<<<dim3(P / 64, Cc / 64, B), 256, 0, stream>>>(Ob, nullptr, Wproj, Yb, 256, 256, 0);
  conv1x1_kernel<<<dim3(P / 64, Cc / 64, B), 256, 0, stream>>>(x, Yb, Wg, Gb, 256, 512, 0);
  bnstat_kernel<<<256, 256, 0, stream>>>(Gb, gamma, beta, scale, shift);
  final_kernel<<<dim3(4, B * Cc), 256, 0, stream>>>(x, Yb, Gb, scale, shift, (float*)d_out);
}

// Round 3
// 203.789 us; speedup vs baseline: 6.4495x; 4.6363x over previous
//
#include <hip/hip_runtime.h>
#include <math.h>

#define B 8
#define Cc 256
#define P 4096
#define NW 64
#define NH 8
#define HD 32
#define TOPK 4
#define SCALE 0.17677669529663687f

typedef unsigned short u16;
typedef __attribute__((ext_vector_type(4))) float f32x4;
typedef __attribute__((ext_vector_type(8))) short s16x8;
typedef __attribute__((ext_vector_type(4))) unsigned short u16x4;

#define MFMA(a, b, c) __builtin_amdgcn_mfma_f32_16x16x32_bf16(a, b, c, 0, 0, 0)

__device__ inline u16 f2bf(float f) {
  unsigned u = __float_as_uint(f);
  return (u16)((u + 0x7fffu + ((u >> 16) & 1u)) >> 16);
}
__device__ inline float bf2f(u16 h) { return __uint_as_float(((unsigned)h) << 16); }

// ---------------------------------------------------------------------------
// f32 -> bf16 flat convert (for weights)
// ---------------------------------------------------------------------------
__global__ __launch_bounds__(256) void cvt_kernel(
    const float* __restrict__ src, u16* __restrict__ dst, int n) {
  int i = (blockIdx.x * 256 + threadIdx.x) * 4;
  if (i < n) {
    float4 v = *(const float4*)(src + i);
    u16x4 o = {f2bf(v.x), f2bf(v.y), f2bf(v.z), f2bf(v.w)};
    *(u16x4*)(dst + i) = o;
  }
}

// ---------------------------------------------------------------------------
// pack: image f32 [b][c][64x64] -> windowed token-major bf16 [b][p'][c]
// x goes to XY (lda 512, first 256 cols), prompt to PT (lda 256)
// ---------------------------------------------------------------------------
__global__ __launch_bounds__(256) void pack_kernel(
    const float* __restrict__ x, const float* __restrict__ prompt,
    u16* __restrict__ XY, u16* __restrict__ PT) {
  __shared__ u16 lds[64][264];
  int y = blockIdx.x;
  int sel = blockIdx.y >> 3, b = blockIdx.y & 7;
  const float* src = (sel ? prompt : x) + (size_t)(b * 256) * 4096 + y * 64;
  int tid = threadIdx.x;
  int xl = tid & 63, cr = tid >> 6;
  for (int step = 0; step < 64; ++step) {
    int c = step * 4 + cr;
    lds[xl][c] = f2bf(src[(size_t)c * 4096 + xl]);
  }
  __syncthreads();
  int t = tid >> 2, c0 = (tid & 3) * 64;
  int n = ((y >> 3) * 8) + (t >> 3);
  int tk = ((y & 7) * 8) + (t & 7);
  size_t prow = (size_t)b * 4096 + n * 64 + tk;
  u16* dst = sel ? (PT + prow * 256 + c0) : (XY + prow * 512 + c0);
#pragma unroll
  for (int cc = 0; cc < 8; ++cc)
    *(s16x8*)(dst + cc * 8) = *(const s16x8*)(&lds[t][c0 + cc * 8]);
}

// ---------------------------------------------------------------------------
// window descriptors (f32, exact) — unchanged
// ---------------------------------------------------------------------------
__global__ __launch_bounds__(256) void desc_kernel(
    const float* __restrict__ x, const float* __restrict__ p,
    float* __restrict__ dx, float* __restrict__ dp) {
  int wid = (blockIdx.x * 256 + threadIdx.x) >> 6;
  int lane = threadIdx.x & 63;
  int sel = wid >> 11;
  int bc = wid & 2047;
  const float* img = (sel ? p : x) + (size_t)bc * P;
  float* d = (sel ? dp : dx) + (size_t)bc * NW;
  for (int wy = 0; wy < 8; ++wy) {
    float s = 0.f;
#pragma unroll
    for (int ty = 0; ty < 8; ++ty)
      s += img[(wy * 8 + ty) * 64 + lane];
    s += __shfl_xor(s, 1);
    s += __shfl_xor(s, 2);
    s += __shfl_xor(s, 4);
    if ((lane & 7) == 0)
      d[wy * 8 + (lane >> 3)] = s * (1.f / 64.f);
  }
}

// ---------------------------------------------------------------------------
// routing (f32, exact) — unchanged
// ---------------------------------------------------------------------------
__global__ __launch_bounds__(64) void route_kernel(
    const float* __restrict__ dx, const float* __restrict__ dp,
    int* __restrict__ routed) {
  int bq = blockIdx.x;
  int b = bq >> 6;
  int q = bq & 63;
  int lane = threadIdx.x;
  const float* dxb = dx + (size_t)b * Cc * NW;
  const float* dpb = dp + (size_t)b * Cc * NW;
  float s = 0.f;
  for (int c = 0; c < Cc; ++c)
    s = fmaf(dxb[c * NW + q], dpb[c * NW + lane], s);
  s *= (1.f / 16.f);
  for (int kk = 0; kk < TOPK; ++kk) {
    float v = s;
    int i = lane;
    for (int off = 32; off; off >>= 1) {
      float ov = __shfl_xor(v, off);
      int oi = __shfl_xor(i, off);
      if (ov > v || (ov == v && oi < i)) { v = ov; i = oi; }
    }
    if (lane == 0) routed[bq * TOPK + kk] = i;
    if (lane == i) s = -INFINITY;
  }
}

// ---------------------------------------------------------------------------
// MFMA GEMM: C[m][o] = sum_k A[m][k] * W[o][k], all bf16, f32 acc.
// M=32768 (b*4096 tokens), N=256, tile 128x128xBK64, 4 waves (2x2 of 64x64).
// mode 0: store bf16 C[m*ldo + o]; mode 1: store C^T channel-major
//         Out[((m>>12)*256 + o)*4096 + (m&4095)]
// ---------------------------------------------------------------------------
__global__ __launch_bounds__(256) void gemm_kernel(
    const u16* __restrict__ A, const u16* __restrict__ W,
    u16* __restrict__ Out, int lda, int K, int ldo, int mode) {
  __shared__ u16 Asm[128 * 64];
  __shared__ u16 Wsm[128 * 64];
  int m0 = blockIdx.x * 128, n0 = blockIdx.y * 128;
  int tid = threadIdx.x;
  int l = tid & 63, wv = tid >> 6;
  int lq = l & 15, g = l >> 4;
  int wm = (wv & 1) * 64, wn = (wv >> 1) * 64;
  f32x4 acc[4][4];
#pragma unroll
  for (int mi = 0; mi < 4; ++mi)
#pragma unroll
    for (int ni = 0; ni < 4; ++ni)
      acc[mi][ni] = (f32x4){0.f, 0.f, 0.f, 0.f};

  for (int k0 = 0; k0 < K; k0 += 64) {
    s16x8 av[4], wvv[4];
#pragma unroll
    for (int i = 0; i < 4; ++i) {
      int s = i * 256 + tid, row = s >> 3, u = s & 7;
      av[i] = *(const s16x8*)(A + (size_t)(m0 + row) * lda + k0 + u * 8);
      wvv[i] = *(const s16x8*)(W + (size_t)(n0 + row) * K + k0 + u * 8);
    }
    __syncthreads();
#pragma unroll
    for (int i = 0; i < 4; ++i) {
      int s = i * 256 + tid, row = s >> 3, u = s & 7;
      int gu = u ^ (row & 7);
      *(s16x8*)(Asm + row * 64 + gu * 8) = av[i];
      *(s16x8*)(Wsm + row * 64 + gu * 8) = wvv[i];
    }
    __syncthreads();
#pragma unroll
    for (int ks = 0; ks < 2; ++ks) {
      s16x8 af[4], bfr[4];
#pragma unroll
      for (int mi = 0; mi < 4; ++mi) {
        int r = wm + 16 * mi + lq;
        af[mi] = *(const s16x8*)(Asm + r * 64 + ((4 * ks + g) ^ (r & 7)) * 8);
      }
#pragma unroll
      for (int ni = 0; ni < 4; ++ni) {
        int r = wn + 16 * ni + lq;
        bfr[ni] = *(const s16x8*)(Wsm + r * 64 + ((4 * ks + g) ^ (r & 7)) * 8);
      }
#pragma unroll
      for (int mi = 0; mi < 4; ++mi)
#pragma unroll
        for (int ni = 0; ni < 4; ++ni)
          acc[mi][ni] = MFMA(af[mi], bfr[ni], acc[mi][ni]);
    }
  }

  if (mode == 0) {
#pragma unroll
    for (int mi = 0; mi < 4; ++mi) {
      size_t mrow = (size_t)(m0 + wm + 16 * mi + 4 * g);
#pragma unroll
      for (int r = 0; r < 4; ++r) {
        u16* orow = Out + (mrow + r) * ldo + n0 + wn + lq;
#pragma unroll
        for (int ni = 0; ni < 4; ++ni)
          orow[16 * ni] = f2bf(acc[mi][ni][r]);
      }
    }
  } else {
    int bb = m0 >> 12;
    int tb = (m0 & 4095) + wm + 4 * g;
#pragma unroll
    for (int ni = 0; ni < 4; ++ni) {
      u16* ocol = Out + ((size_t)(bb * 256) + n0 + wn + 16 * ni + lq) * 4096 + tb;
#pragma unroll
      for (int mi = 0; mi < 4; ++mi) {
        u16x4 pk = {f2bf(acc[mi][ni][0]), f2bf(acc[mi][ni][1]),
                    f2bf(acc[mi][ni][2]), f2bf(acc[mi][ni][3])};
        *(u16x4*)(ocol + 16 * mi) = pk;
      }
    }
  }
}

// ---------------------------------------------------------------------------
// MFMA attention: block=(b,n), 8 waves=heads. Q,K token-major bf16 [p'][256];
// V channel-major bf16 [b*256+c][4096]. S^T = mfma(K, Q^T); in-register
// no-max softmax; P -> bf16 -> per-wave swizzled LDS; O = mfma(P, V).
// Output token-major bf16.
// ---------------------------------------------------------------------------
__global__ __launch_bounds__(512) void attn_kernel(
    const u16* __restrict__ Qb, const u16* __restrict__ Kb,
    const u16* __restrict__ Vt, const int* __restrict__ routed,
    u16* __restrict__ Ob) {
  __shared__ u16 Plds[8 * 4096];
  int bn = blockIdx.x, b = bn >> 6, n = bn & 63;
  int h = threadIdx.x >> 6, l = threadIdx.x & 63;
  int lq = l & 15, g = l >> 4;
  char* Pw = (char*)(Plds + h * 4096);

  const u16* Qrow = Qb + ((size_t)(b * 4096) + n * 64) * 256 + h * 32 + g * 8;
  s16x8 qf[4];
#pragma unroll
  for (int qi = 0; qi < 4; ++qi)
    qf[qi] = *(const s16x8*)(Qrow + (16 * qi + lq) * 256);

  f32x4 acc[4][2];
#pragma unroll
  for (int qi = 0; qi < 4; ++qi) {
    acc[qi][0] = (f32x4){0.f, 0.f, 0.f, 0.f};
    acc[qi][1] = (f32x4){0.f, 0.f, 0.f, 0.f};
  }
  float denom[4] = {0.f, 0.f, 0.f, 0.f};
  const f32x4 zero4 = {0.f, 0.f, 0.f, 0.f};
  const int* rptr = routed + bn * TOPK;

  for (int kk = 0; kk < TOPK; ++kk) {
    int pw = __builtin_amdgcn_readfirstlane(rptr[kk]);
    const u16* Krow = Kb + ((size_t)(b * 4096) + pw * 64) * 256 + h * 32 + g * 8;
    const u16* Vrow = Vt + ((size_t)(b * 256) + h * 32 + lq) * 4096 + pw * 64 + 8 * g;
#pragma unroll
    for (int kvi = 0; kvi < 4; ++kvi) {
      s16x8 kf = *(const s16x8*)(Krow + (16 * kvi + lq) * 256);
      f32x4 sv[4];
#pragma unroll
      for (int qi = 0; qi < 4; ++qi)
        sv[qi] = MFMA(kf, qf[qi], zero4);
#pragma unroll
      for (int qi = 0; qi < 4; ++qi) {
        float p0 = __expf(sv[qi][0] * SCALE);
        float p1 = __expf(sv[qi][1] * SCALE);
        float p2 = __expf(sv[qi][2] * SCALE);
        float p3 = __expf(sv[qi][3] * SCALE);
        denom[qi] += (p0 + p1) + (p2 + p3);
        uint2 pk;
        pk.x = (unsigned)f2bf(p0) | ((unsigned)f2bf(p1) << 16);
        pk.y = (unsigned)f2bf(p2) | ((unsigned)f2bf(p3) << 16);
        int q = 16 * qi + lq;
        int kvb = (16 * kvi + 4 * g) * 2;
        *(uint2*)(Pw + q * 128 + (kvb ^ ((q & 7) << 4))) = pk;
      }
    }
#pragma unroll
    for (int s = 0; s < 2; ++s) {
      s16x8 vf[2];
#pragma unroll
      for (int di = 0; di < 2; ++di)
        vf[di] = *(const s16x8*)(Vrow + (size_t)(16 * di) * 4096 + 32 * s);
#pragma unroll
      for (int qi = 0; qi < 4; ++qi) {
        int q = 16 * qi + lq;
        s16x8 pf = *(const s16x8*)(Pw + q * 128 +
                                   ((64 * s + 16 * g) ^ ((q & 7) << 4)));
#pragma unroll
        for (int di = 0; di < 2; ++di)
          acc[qi][di] = MFMA(pf, vf[di], acc[qi][di]);
      }
    }
  }

#pragma unroll
  for (int qi = 0; qi < 4; ++qi) {
    denom[qi] += __shfl_xor(denom[qi], 16);
    denom[qi] += __shfl_xor(denom[qi], 32);
  }
  u16* Orow = Ob + ((size_t)(b * 4096) + n * 64) * 256 + h * 32;
#pragma unroll
  for (int qi = 0; qi < 4; ++qi) {
    float inv = 1.f / denom[qi];
#pragma unroll
    for (int r = 0; r < 4; ++r) {
      float nr = __shfl(inv, 4 * g + r);
#pragma unroll
      for (int di = 0; di < 2; ++di)
        Orow[(16 * qi + 4 * g + r) * 256 + 16 * di + lq] =
            f2bf(acc[qi][di][r] * nr);
    }
  }
}

// ---------------------------------------------------------------------------
// BN stats, deterministic two-pass: per-block partial sums over 256 rows
// ---------------------------------------------------------------------------
__global__ __launch_bounds__(256) void bnstat_kernel(
    const u16* __restrict__ G, float* __restrict__ pS, float* __restrict__ pSS) {
  int blk = blockIdx.x;
  int tid = threadIdx.x;
  int rg = tid >> 5, c0 = (tid & 31) * 8;
  float s[8] = {0.f, 0.f, 0.f, 0.f, 0.f, 0.f, 0.f, 0.f};
  float ss[8] = {0.f, 0.f, 0.f, 0.f, 0.f, 0.f, 0.f, 0.f};
  for (int rr = 0; rr < 32; ++rr) {
    int row = blk * 256 + rr * 8 + rg;
    s16x8 v = *(const s16x8*)(G + (size_t)row * 256 + c0);
#pragma unroll
    for (int j = 0; j < 8; ++j) {
      float f = bf2f((u16)v[j]);
      s[j] += f;
      ss[j] = fmaf(f, f, ss[j]);
    }
  }
  __shared__ float redS[8][256];
  __shared__ float redSS[8][256];
#pragma unroll
  for (int j = 0; j < 8; ++j) {
    redS[rg][c0 + j] = s[j];
    redSS[rg][c0 + j] = ss[j];
  }
  __syncthreads();
  int c = tid;
  float S = 0.f, SS = 0.f;
#pragma unroll
  for (int g2 = 0; g2 < 8; ++g2) {
    S += redS[g2][c];
    SS += redSS[g2][c];
  }
  pS[blk * 256 + c] = S;
  pSS[blk * 256 + c] = SS;
}

__global__ __launch_bounds__(256) void bnfin_kernel(
    const float* __restrict__ pS, const float* __restrict__ pSS,
    const float* __restrict__ gamma, const float* __restrict__ beta,
    float* __restrict__ scale, float* __restrict__ shift) {
  int c = threadIdx.x;
  float S = 0.f, SS = 0.f;
  for (int b2 = 0; b2 < 128; ++b2) {
    S += pS[b2 * 256 + c];
    SS += pSS[b2 * 256 + c];
  }
  const float invN = 1.f / 32768.f;
  float mean = S * invN;
  float var = SS * invN - mean * mean;
  float sc = rsqrtf(var + 1e-5f) * gamma[c];
  scale[c] = sc;
  shift[c] = beta[c] - mean * sc;
}

// ---------------------------------------------------------------------------
// final: out[b][c][pix] = x + sigmoid(g*scale+shift) * y
// Y in XY[..][256..511], G token-major bf16. block=(b,window), 8x8 reg tiles.
// ---------------------------------------------------------------------------
__global__ __launch_bounds__(256) void final_kernel(
    const float* __restrict__ x, const u16* __restrict__ XY,
    const u16* __restrict__ GT, const float* __restrict__ scale,
    const float* __restrict__ shift, float* __restrict__ out) {
  int n = blockIdx.x, b = blockIdx.y;
  int tid = threadIdx.x;
  int co = tid & 31, ty = tid >> 5;
  int wy = n >> 3, wx = n & 7;
  size_t prow = (size_t)b * 4096 + n * 64 + ty * 8;
  float sc[8], sh[8];
#pragma unroll
  for (int j = 0; j < 8; ++j) {
    sc[j] = scale[co * 8 + j];
    sh[j] = shift[co * 8 + j];
  }
  s16x8 yv[8], gv[8];
#pragma unroll
  for (int tx = 0; tx < 8; ++tx) {
    yv[tx] = *(const s16x8*)(XY + (prow + tx) * 512 + 256 + co * 8);
    gv[tx] = *(const s16x8*)(GT + (prow + tx) * 256 + co * 8);
  }
#pragma unroll
  for (int j = 0; j < 8; ++j) {
    size_t abase = ((size_t)b * 256 + co * 8 + j) * 4096 +
                   (wy * 8 + ty) * 64 + wx * 8;
    float r[8];
#pragma unroll
    for (int tx = 0; tx < 8; ++tx) {
      float gate = 1.f / (1.f + __expf(-fmaf(bf2f((u16)gv[tx][j]), sc[j], sh[j])));
      r[tx] = gate * bf2f((u16)yv[tx][j]);
    }
    const float4* xp = (const float4*)(x + abase);
    float4 x0 = xp[0], x1 = xp[1];
    float4 o0, o1;
    o0.x = x0.x + r[0]; o0.y = x0.y + r[1]; o0.z = x0.z + r[2]; o0.w = x0.w + r[3];
    o1.x = x1.x + r[4]; o1.y = x1.y + r[5]; o1.z = x1.z + r[6]; o1.w = x1.w + r[7];
    ((float4*)(out + abase))[0] = o0;
    ((float4*)(out + abase))[1] = o1;
  }
}

// ---------------------------------------------------------------------------
extern "C" void kernel_launch(void* const* d_in, const int* in_sizes, int n_in,
                              void* d_out, int out_size, void* d_ws, size_t ws_size,
                              hipStream_t stream) {
  const float* x      = (const float*)d_in[0];
  const float* prompt = (const float*)d_in[1];
  const float* Wq     = (const float*)d_in[2];
  const float* Wk     = (const float*)d_in[3];
  const float* Wv     = (const float*)d_in[4];
  const float* Wproj  = (const float*)d_in[5];
  const float* Wg     = (const float*)d_in[6];
  const float* gamma  = (const float*)d_in[7];
  const float* beta   = (const float*)d_in[8];

  char* wsb = (char*)d_ws;
  u16* XY    = (u16*)(wsb + 0);           // [b][p'][512]: x | y
  u16* PT    = (u16*)(wsb + 33554432);    // prompt [b][p'][256]
  u16* QT    = (u16*)(wsb + 50331648);    // Q [b][p'][256]
  u16* KT    = (u16*)(wsb + 67108864);    // K [b][p'][256]
  u16* VT    = (u16*)(wsb + 83886080);    // V channel-major [b*256+c][4096]
  u16* OT    = (u16*)(wsb + 100663296);   // attn out [b][p'][256]
  u16* Wbf   = (u16*)(wsb + 117440512);   // Wq|Wk|Wv|Wproj|Wg bf16
  float* dx  = (float*)(wsb + 118226944);
  float* dp  = (float*)(wsb + 118751232);
  float* pS  = (float*)(wsb + 119275520);
  float* pSS = (float*)(wsb + 119406592);
  float* scl = (float*)(wsb + 119537664);
  float* shf = (float*)(wsb + 119538688);
  int* routed = (int*)(wsb + 119539712);
  u16* GT = QT;  // reuse: Q dead after attention

  cvt_kernel<<<64, 256, 0, stream>>>(Wq, Wbf, 65536);
  cvt_kernel<<<64, 256, 0, stream>>>(Wk, Wbf + 65536, 65536);
  cvt_kernel<<<64, 256, 0, stream>>>(Wv, Wbf + 131072, 65536);
  cvt_kernel<<<64, 256, 0, stream>>>(Wproj, Wbf + 196608, 65536);
  cvt_kernel<<<128, 256, 0, stream>>>(Wg, Wbf + 262144, 131072);

  pack_kernel<<<dim3(64, 16), 256, 0, stream>>>(x, prompt, XY, PT);
  desc_kernel<<<1024, 256, 0, stream>>>(x, prompt, dx, dp);
  route_kernel<<<B * NW, 64, 0, stream>>>(dx, dp, routed);

  gemm_kernel<<<dim3(256, 2), 256, 0, stream>>>(XY, Wbf, QT, 512, 256, 256, 0);
  gemm_kernel<<<dim3(256, 2), 256, 0, stream>>>(PT, Wbf + 65536, KT, 256, 256, 256, 0);
  gemm_kernel<<<dim3(256, 2), 256, 0, stream>>>(PT, Wbf + 131072, VT, 256, 256, 0, 1);

  attn_kernel<<<B * NW, 512, 0, stream>>>(QT, KT, VT, routed, OT);

  gemm_kernel<<<dim3(256, 2), 256, 0, stream>>>(OT, Wbf + 196608, XY + 256, 256, 256, 512, 0);
  gemm_kernel<<<dim3(256, 2), 256, 0, stream>>>(XY, Wbf + 262144, GT, 512, 512, 256, 0);

  bnstat_kernel<<<128, 256, 0, stream>>>(GT, pS, pSS);
  bnfin_kernel<<<1, 256, 0, stream>>>(pS, pSS, gamma, beta, scl, shf);
  final_kernel<<<dim3(NW, B), 256, 0, stream>>>(x, XY, GT, scl, shf, (float*)d_out);
}

// Round 4
// 188.301 us; speedup vs baseline: 6.9799x; 1.0822x over previous
//
#include <hip/hip_runtime.h>
#include <math.h>

#define B 8
#define Cc 256
#define P 4096
#define NW 64
#define NH 8
#define HD 32
#define TOPK 4
#define SCALE 0.17677669529663687f

typedef unsigned short u16;
typedef __attribute__((ext_vector_type(4))) float f32x4;
typedef __attribute__((ext_vector_type(8))) short s16x8;
typedef __attribute__((ext_vector_type(4))) unsigned short u16x4;

#define MFMA(a, b, c) __builtin_amdgcn_mfma_f32_16x16x32_bf16(a, b, c, 0, 0, 0)

__device__ inline u16 f2bf(float f) {
  unsigned u = __float_as_uint(f);
  return (u16)((u + 0x7fffu + ((u >> 16) & 1u)) >> 16);
}
__device__ inline float bf2f(u16 h) { return __uint_as_float(((unsigned)h) << 16); }

// ---------------------------------------------------------------------------
// weights f32 -> bf16, all five in one launch (blockIdx.y = job)
// ---------------------------------------------------------------------------
__global__ __launch_bounds__(256) void wcvt_kernel(
    const float* __restrict__ Wq, const float* __restrict__ Wk,
    const float* __restrict__ Wv, const float* __restrict__ Wproj,
    const float* __restrict__ Wg, u16* __restrict__ Wbf) {
  int job = blockIdx.y;
  const float* src;
  u16* dst;
  int n;
  switch (job) {
    case 0: src = Wq;    dst = Wbf;          n = 65536;  break;
    case 1: src = Wk;    dst = Wbf + 65536;  n = 65536;  break;
    case 2: src = Wv;    dst = Wbf + 131072; n = 65536;  break;
    case 3: src = Wproj; dst = Wbf + 196608; n = 65536;  break;
    default: src = Wg;   dst = Wbf + 262144; n = 131072; break;
  }
  int i = (blockIdx.x * 256 + threadIdx.x) * 4;
  if (i < n) {
    float4 v = *(const float4*)(src + i);
    u16x4 o = {f2bf(v.x), f2bf(v.y), f2bf(v.z), f2bf(v.w)};
    *(u16x4*)(dst + i) = o;
  }
}

// ---------------------------------------------------------------------------
// pack: image f32 [b][c][64x64] -> windowed token-major bf16, PLUS f32
// per-row window partial sums (desc fusion). Pd layout [sb][y][wx][c].
// ---------------------------------------------------------------------------
__global__ __launch_bounds__(256) void pack_kernel(
    const float* __restrict__ x, const float* __restrict__ prompt,
    u16* __restrict__ XY, u16* __restrict__ PT, float* __restrict__ Pd) {
  __shared__ u16 lds[64][264];
  int y = blockIdx.x;
  int sb = blockIdx.y;
  int sel = sb >> 3, b = sb & 7;
  const float* src = (sel ? prompt : x) + (size_t)(b * 256) * 4096 + y * 64;
  int tid = threadIdx.x;
  int xl = tid & 63, cr = tid >> 6;
  float* pd = Pd + ((size_t)sb * 64 + y) * 2048;
  for (int step = 0; step < 64; ++step) {
    int c = step * 4 + cr;
    float f = src[(size_t)c * 4096 + xl];
    lds[xl][c] = f2bf(f);
    float s = f;
    s += __shfl_xor(s, 1);
    s += __shfl_xor(s, 2);
    s += __shfl_xor(s, 4);
    if ((xl & 7) == 0) pd[(xl >> 3) * 256 + c] = s;
  }
  __syncthreads();
  int t = tid >> 2, c0 = (tid & 3) * 64;
  int n = ((y >> 3) * 8) + (t >> 3);
  int tk = ((y & 7) * 8) + (t & 7);
  size_t prow = (size_t)b * 4096 + n * 64 + tk;
  u16* dst = sel ? (PT + prow * 256 + c0) : (XY + prow * 512 + c0);
#pragma unroll
  for (int cc = 0; cc < 8; ++cc)
    *(s16x8*)(dst + cc * 8) = *(const s16x8*)(&lds[t][c0 + cc * 8]);
}

// ---------------------------------------------------------------------------
// reduce partials -> descriptors [b][c][n] (f32, deterministic order)
// ---------------------------------------------------------------------------
__global__ __launch_bounds__(256) void dred_kernel(
    const float* __restrict__ Pd, float* __restrict__ dx, float* __restrict__ dp) {
  int sb = blockIdx.x;
  int sel = sb >> 3, b = sb & 7;
  int c = threadIdx.x;
  float* dst = (sel ? dp : dx) + ((size_t)b * 256 + c) * 64;
  const float* src = Pd + (size_t)sb * 64 * 2048;
#pragma unroll
  for (int nn = 0; nn < 8; ++nn) {
    int n = blockIdx.y * 8 + nn;
    int wy = n >> 3, wx = n & 7;
    float s = 0.f;
#pragma unroll
    for (int yl = 0; yl < 8; ++yl)
      s += src[((wy * 8 + yl) * 8 + wx) * 256 + c];
    dst[n] = s * (1.f / 64.f);
  }
}

// ---------------------------------------------------------------------------
// routing (f32, exact)
// ---------------------------------------------------------------------------
__global__ __launch_bounds__(64) void route_kernel(
    const float* __restrict__ dx, const float* __restrict__ dp,
    int* __restrict__ routed) {
  int bq = blockIdx.x;
  int b = bq >> 6;
  int q = bq & 63;
  int lane = threadIdx.x;
  const float* dxb = dx + (size_t)b * Cc * NW;
  const float* dpb = dp + (size_t)b * Cc * NW;
  float s = 0.f;
  for (int c = 0; c < Cc; ++c)
    s = fmaf(dxb[c * NW + q], dpb[c * NW + lane], s);
  s *= (1.f / 16.f);
  for (int kk = 0; kk < TOPK; ++kk) {
    float v = s;
    int i = lane;
    for (int off = 32; off; off >>= 1) {
      float ov = __shfl_xor(v, off);
      int oi = __shfl_xor(i, off);
      if (ov > v || (ov == v && oi < i)) { v = ov; i = oi; }
    }
    if (lane == 0) routed[bq * TOPK + kk] = i;
    if (lane == i) s = -INFINITY;
  }
}

// ---------------------------------------------------------------------------
// shared MFMA GEMM core: acc += A[m0..+128][k] * W[n0..+128][k]
// ---------------------------------------------------------------------------
__device__ __forceinline__ void gemm_core(
    const u16* __restrict__ A, int lda, const u16* __restrict__ W, int K,
    int m0, int n0, int tid, u16* Asm, u16* Wsm, f32x4 (&acc)[4][4]) {
  int l = tid & 63, wv = tid >> 6;
  int lq = l & 15, g = l >> 4;
  int wm = (wv & 1) * 64, wn = (wv >> 1) * 64;
  for (int k0 = 0; k0 < K; k0 += 64) {
    s16x8 av[4], wvv[4];
#pragma unroll
    for (int i = 0; i < 4; ++i) {
      int s = i * 256 + tid, row = s >> 3, u = s & 7;
      av[i] = *(const s16x8*)(A + (size_t)(m0 + row) * lda + k0 + u * 8);
      wvv[i] = *(const s16x8*)(W + (size_t)(n0 + row) * K + k0 + u * 8);
    }
    __syncthreads();
#pragma unroll
    for (int i = 0; i < 4; ++i) {
      int s = i * 256 + tid, row = s >> 3, u = s & 7;
      int gu = u ^ (row & 7);
      *(s16x8*)(Asm + row * 64 + gu * 8) = av[i];
      *(s16x8*)(Wsm + row * 64 + gu * 8) = wvv[i];
    }
    __syncthreads();
#pragma unroll
    for (int ks = 0; ks < 2; ++ks) {
      s16x8 af[4], bfr[4];
#pragma unroll
      for (int mi = 0; mi < 4; ++mi) {
        int r = wm + 16 * mi + lq;
        af[mi] = *(const s16x8*)(Asm + r * 64 + ((4 * ks + g) ^ (r & 7)) * 8);
      }
#pragma unroll
      for (int ni = 0; ni < 4; ++ni) {
        int r = wn + 16 * ni + lq;
        bfr[ni] = *(const s16x8*)(Wsm + r * 64 + ((4 * ks + g) ^ (r & 7)) * 8);
      }
#pragma unroll
      for (int mi = 0; mi < 4; ++mi)
#pragma unroll
        for (int ni = 0; ni < 4; ++ni)
          acc[mi][ni] = MFMA(af[mi], bfr[ni], acc[mi][ni]);
    }
  }
}

__device__ __forceinline__ void store_rowmajor(
    f32x4 (&acc)[4][4], u16* __restrict__ Out, int ldo,
    size_t mbase, int nbase, int lq, int g) {
#pragma unroll
  for (int mi = 0; mi < 4; ++mi) {
    size_t mrow = mbase + 16 * mi + 4 * g;
#pragma unroll
    for (int r = 0; r < 4; ++r) {
      u16* orow = Out + (mrow + r) * ldo + nbase + lq;
#pragma unroll
      for (int ni = 0; ni < 4; ++ni)
        orow[16 * ni] = f2bf(acc[mi][ni][r]);
    }
  }
}

__device__ __forceinline__ void store_chanmajor(
    f32x4 (&acc)[4][4], u16* __restrict__ Out,
    int bb, int tb, int cbase, int lq) {
#pragma unroll
  for (int ni = 0; ni < 4; ++ni) {
    u16* ocol = Out + ((size_t)(bb * 256) + cbase + 16 * ni + lq) * 4096 + tb;
#pragma unroll
    for (int mi = 0; mi < 4; ++mi) {
      u16x4 pk = {f2bf(acc[mi][ni][0]), f2bf(acc[mi][ni][1]),
                  f2bf(acc[mi][ni][2]), f2bf(acc[mi][ni][3])};
      *(u16x4*)(ocol + 16 * mi) = pk;
    }
  }
}

// ---------------------------------------------------------------------------
// Q/K/V in one launch: jy<2 -> Q (A=x part of XY); jy 2..5 -> K|V (A=PT)
// ---------------------------------------------------------------------------
__global__ __launch_bounds__(256) void qkv_kernel(
    const u16* __restrict__ XY, const u16* __restrict__ PT,
    const u16* __restrict__ Wbf, u16* __restrict__ QT,
    u16* __restrict__ KT, u16* __restrict__ VT) {
  __shared__ u16 Asm[8192], Wsm[8192];
  int jy = blockIdx.y, m0 = blockIdx.x * 128;
  int tid = threadIdx.x;
  int l = tid & 63, wv = tid >> 6;
  int lq = l & 15, g = l >> 4;
  int wm = (wv & 1) * 64, wn = (wv >> 1) * 64;
  f32x4 acc[4][4];
#pragma unroll
  for (int mi = 0; mi < 4; ++mi)
#pragma unroll
    for (int ni = 0; ni < 4; ++ni)
      acc[mi][ni] = (f32x4){0.f, 0.f, 0.f, 0.f};

  const u16* A;
  const u16* W;
  int lda, n0;
  if (jy < 2) { A = XY; lda = 512; W = Wbf; n0 = jy * 128; }
  else        { A = PT; lda = 256; W = Wbf + 65536; n0 = (jy - 2) * 128; }
  gemm_core(A, lda, W, 256, m0, n0, tid, Asm, Wsm, acc);

  if (jy < 2) {
    store_rowmajor(acc, QT, 256, (size_t)(m0 + wm), n0 + wn, lq, g);
  } else if (n0 < 256) {
    store_rowmajor(acc, KT, 256, (size_t)(m0 + wm), n0 + wn, lq, g);
  } else {
    store_chanmajor(acc, VT, m0 >> 12, (m0 & 4095) + wm + 4 * g,
                    (n0 - 256) + wn, lq);
  }
}

// ---------------------------------------------------------------------------
// proj: y = Wproj * o  (A=OT), stores into XY cols 256..511
// ---------------------------------------------------------------------------
__global__ __launch_bounds__(256) void proj_kernel(
    const u16* __restrict__ OT, const u16* __restrict__ Wbf,
    u16* __restrict__ XY) {
  __shared__ u16 Asm[8192], Wsm[8192];
  int m0 = blockIdx.x * 128, n0 = blockIdx.y * 128;
  int tid = threadIdx.x;
  int l = tid & 63, wv = tid >> 6;
  int lq = l & 15, g = l >> 4;
  int wm = (wv & 1) * 64, wn = (wv >> 1) * 64;
  f32x4 acc[4][4];
#pragma unroll
  for (int mi = 0; mi < 4; ++mi)
#pragma unroll
    for (int ni = 0; ni < 4; ++ni)
      acc[mi][ni] = (f32x4){0.f, 0.f, 0.f, 0.f};
  gemm_core(OT, 256, Wbf + 196608, 256, m0, n0, tid, Asm, Wsm, acc);
  store_rowmajor(acc, XY + 256, 512, (size_t)(m0 + wm), n0 + wn, lq, g);
}

// ---------------------------------------------------------------------------
// gate: G = Wg * [x|y] (A=XY, K=512) + BN partial sums from f32 acc
// ---------------------------------------------------------------------------
__global__ __launch_bounds__(256) void gate_kernel(
    const u16* __restrict__ XY, const u16* __restrict__ Wbf,
    u16* __restrict__ GT, float* __restrict__ pS, float* __restrict__ pSS) {
  __shared__ u16 Asm[8192], Wsm[8192];
  int m0 = blockIdx.x * 128, n0 = blockIdx.y * 128;
  int tid = threadIdx.x;
  int l = tid & 63, wv = tid >> 6;
  int lq = l & 15, g = l >> 4;
  int wm = (wv & 1) * 64, wn = (wv >> 1) * 64;
  f32x4 acc[4][4];
#pragma unroll
  for (int mi = 0; mi < 4; ++mi)
#pragma unroll
    for (int ni = 0; ni < 4; ++ni)
      acc[mi][ni] = (f32x4){0.f, 0.f, 0.f, 0.f};
  gemm_core(XY, 512, Wbf + 262144, 512, m0, n0, tid, Asm, Wsm, acc);
  store_rowmajor(acc, GT, 256, (size_t)(m0 + wm), n0 + wn, lq, g);

  // BN partials over this block's 128 rows
  float cs[4], cq[4];
#pragma unroll
  for (int ni = 0; ni < 4; ++ni) {
    float s = 0.f, q2 = 0.f;
#pragma unroll
    for (int mi = 0; mi < 4; ++mi)
#pragma unroll
      for (int r = 0; r < 4; ++r) {
        float v = acc[mi][ni][r];
        s += v;
        q2 = fmaf(v, v, q2);
      }
    cs[ni] = s;
    cq[ni] = q2;
  }
#pragma unroll
  for (int ni = 0; ni < 4; ++ni) {
    cs[ni] += __shfl_xor(cs[ni], 16);
    cs[ni] += __shfl_xor(cs[ni], 32);
    cq[ni] += __shfl_xor(cq[ni], 16);
    cq[ni] += __shfl_xor(cq[ni], 32);
  }
  float* sS = (float*)Asm;
  float* sQ = sS + 128;
  __syncthreads();
  if ((wv & 1) == 0 && g == 0) {
#pragma unroll
    for (int ni = 0; ni < 4; ++ni) {
      int col = wn + 16 * ni + lq;
      sS[col] = cs[ni];
      sQ[col] = cq[ni];
    }
  }
  __syncthreads();
  if ((wv & 1) == 1 && g == 0) {
#pragma unroll
    for (int ni = 0; ni < 4; ++ni) {
      int col = wn + 16 * ni + lq;
      sS[col] += cs[ni];
      sQ[col] += cq[ni];
    }
  }
  __syncthreads();
  if (tid < 128) {
    pS[(size_t)blockIdx.x * 256 + n0 + tid] = sS[tid];
    pSS[(size_t)blockIdx.x * 256 + n0 + tid] = sQ[tid];
  }
}

// ---------------------------------------------------------------------------
// MFMA attention (unchanged from R3)
// ---------------------------------------------------------------------------
__global__ __launch_bounds__(512) void attn_kernel(
    const u16* __restrict__ Qb, const u16* __restrict__ Kb,
    const u16* __restrict__ Vt, const int* __restrict__ routed,
    u16* __restrict__ Ob) {
  __shared__ u16 Plds[8 * 4096];
  int bn = blockIdx.x, b = bn >> 6, n = bn & 63;
  int h = threadIdx.x >> 6, l = threadIdx.x & 63;
  int lq = l & 15, g = l >> 4;
  char* Pw = (char*)(Plds + h * 4096);

  const u16* Qrow = Qb + ((size_t)(b * 4096) + n * 64) * 256 + h * 32 + g * 8;
  s16x8 qf[4];
#pragma unroll
  for (int qi = 0; qi < 4; ++qi)
    qf[qi] = *(const s16x8*)(Qrow + (16 * qi + lq) * 256);

  f32x4 acc[4][2];
#pragma unroll
  for (int qi = 0; qi < 4; ++qi) {
    acc[qi][0] = (f32x4){0.f, 0.f, 0.f, 0.f};
    acc[qi][1] = (f32x4){0.f, 0.f, 0.f, 0.f};
  }
  float denom[4] = {0.f, 0.f, 0.f, 0.f};
  const f32x4 zero4 = {0.f, 0.f, 0.f, 0.f};
  const int* rptr = routed + bn * TOPK;

  for (int kk = 0; kk < TOPK; ++kk) {
    int pw = __builtin_amdgcn_readfirstlane(rptr[kk]);
    const u16* Krow = Kb + ((size_t)(b * 4096) + pw * 64) * 256 + h * 32 + g * 8;
    const u16* Vrow = Vt + ((size_t)(b * 256) + h * 32 + lq) * 4096 + pw * 64 + 8 * g;
#pragma unroll
    for (int kvi = 0; kvi < 4; ++kvi) {
      s16x8 kf = *(const s16x8*)(Krow + (16 * kvi + lq) * 256);
      f32x4 sv[4];
#pragma unroll
      for (int qi = 0; qi < 4; ++qi)
        sv[qi] = MFMA(kf, qf[qi], zero4);
#pragma unroll
      for (int qi = 0; qi < 4; ++qi) {
        float p0 = __expf(sv[qi][0] * SCALE);
        float p1 = __expf(sv[qi][1] * SCALE);
        float p2 = __expf(sv[qi][2] * SCALE);
        float p3 = __expf(sv[qi][3] * SCALE);
        denom[qi] += (p0 + p1) + (p2 + p3);
        uint2 pk;
        pk.x = (unsigned)f2bf(p0) | ((unsigned)f2bf(p1) << 16);
        pk.y = (unsigned)f2bf(p2) | ((unsigned)f2bf(p3) << 16);
        int q = 16 * qi + lq;
        int kvb = (16 * kvi + 4 * g) * 2;
        *(uint2*)(Pw + q * 128 + (kvb ^ ((q & 7) << 4))) = pk;
      }
    }
#pragma unroll
    for (int s = 0; s < 2; ++s) {
      s16x8 vf[2];
#pragma unroll
      for (int di = 0; di < 2; ++di)
        vf[di] = *(const s16x8*)(Vrow + (size_t)(16 * di) * 4096 + 32 * s);
#pragma unroll
      for (int qi = 0; qi < 4; ++qi) {
        int q = 16 * qi + lq;
        s16x8 pf = *(const s16x8*)(Pw + q * 128 +
                                   ((64 * s + 16 * g) ^ ((q & 7) << 4)));
#pragma unroll
        for (int di = 0; di < 2; ++di)
          acc[qi][di] = MFMA(pf, vf[di], acc[qi][di]);
      }
    }
  }

#pragma unroll
  for (int qi = 0; qi < 4; ++qi) {
    denom[qi] += __shfl_xor(denom[qi], 16);
    denom[qi] += __shfl_xor(denom[qi], 32);
  }
  u16* Orow = Ob + ((size_t)(b * 4096) + n * 64) * 256 + h * 32;
#pragma unroll
  for (int qi = 0; qi < 4; ++qi) {
    float inv = 1.f / denom[qi];
#pragma unroll
    for (int r = 0; r < 4; ++r) {
      float nr = __shfl(inv, 4 * g + r);
#pragma unroll
      for (int di = 0; di < 2; ++di)
        Orow[(16 * qi + 4 * g + r) * 256 + 16 * di + lq] =
            f2bf(acc[qi][di][r] * nr);
    }
  }
}

// ---------------------------------------------------------------------------
// BN finalize: sum 256 block-partials per channel -> scale/shift
// ---------------------------------------------------------------------------
__global__ __launch_bounds__(1024) void bnfin_kernel(
    const float* __restrict__ pS, const float* __restrict__ pSS,
    const float* __restrict__ gamma, const float* __restrict__ beta,
    float* __restrict__ scale, float* __restrict__ shift) {
  int tid = threadIdx.x;
  int c = tid >> 2, part = tid & 3;
  float S = 0.f, SS = 0.f;
  for (int m = part * 64; m < part * 64 + 64; ++m) {
    S += pS[m * 256 + c];
    SS += pSS[m * 256 + c];
  }
  __shared__ float rS[4][256], rQ[4][256];
  rS[part][c] = S;
  rQ[part][c] = SS;
  __syncthreads();
  if (tid < 256) {
    int cc = tid;
    float S2 = rS[0][cc] + rS[1][cc] + rS[2][cc] + rS[3][cc];
    float Q2 = rQ[0][cc] + rQ[1][cc] + rQ[2][cc] + rQ[3][cc];
    const float invN = 1.f / 32768.f;
    float mean = S2 * invN;
    float var = Q2 * invN - mean * mean;
    float sc = rsqrtf(var + 1e-5f) * gamma[cc];
    scale[cc] = sc;
    shift[cc] = beta[cc] - mean * sc;
  }
}

// ---------------------------------------------------------------------------
// final: block = (image row y, b). LDS-stage Y,G (token-major) with chunk
// XOR swizzle; compute phase lane = pixel -> fully coalesced x/out.
// ---------------------------------------------------------------------------
__global__ __launch_bounds__(256) void final_kernel(
    const float* __restrict__ x, const u16* __restrict__ XY,
    const u16* __restrict__ GT, const float* __restrict__ scale,
    const float* __restrict__ shift, float* __restrict__ out) {
  __shared__ u16 Yl[64 * 256];
  __shared__ u16 Gl[64 * 256];
  __shared__ float sSc[256], sSh[256];
  int y = blockIdx.x, b = blockIdx.y;
  int tid = threadIdx.x;
  sSc[tid] = scale[tid];
  sSh[tid] = shift[tid];
  {
    int r = tid >> 2;
    int n = ((y >> 3) << 3) + (r >> 3);
    int t = ((y & 7) << 3) + (r & 7);
    size_t prow = (size_t)b * 4096 + n * 64 + t;
    const u16* ysrc = XY + prow * 512 + 256;
    const u16* gsrc = GT + prow * 256;
#pragma unroll
    for (int cc = 0; cc < 8; ++cc) {
      int chunk = (tid & 3) * 8 + cc;
      int off = r * 256 + ((chunk ^ (r & 31)) << 3);
      *(s16x8*)(Yl + off) = *(const s16x8*)(ysrc + chunk * 8);
      *(s16x8*)(Gl + off) = *(const s16x8*)(gsrc + chunk * 8);
    }
  }
  __syncthreads();
  int lane = tid & 63, wq = tid >> 6;
  size_t base = (size_t)(b * 256) * 4096 + y * 64 + lane;
#pragma unroll 2
  for (int ch = 0; ch < 8; ++ch) {
    int chunk = wq * 8 + ch;
    int off = lane * 256 + ((chunk ^ (lane & 31)) << 3);
    s16x8 yv = *(const s16x8*)(Yl + off);
    s16x8 gv = *(const s16x8*)(Gl + off);
#pragma unroll
    for (int j = 0; j < 8; ++j) {
      int c = chunk * 8 + j;
      size_t a = base + (size_t)c * 4096;
      float gate = 1.f / (1.f + __expf(-fmaf(bf2f((u16)gv[j]), sSc[c], sSh[c])));
      out[a] = x[a] + gate * bf2f((u16)yv[j]);
    }
  }
}

// ---------------------------------------------------------------------------
extern "C" void kernel_launch(void* const* d_in, const int* in_sizes, int n_in,
                              void* d_out, int out_size, void* d_ws, size_t ws_size,
                              hipStream_t stream) {
  const float* x      = (const float*)d_in[0];
  const float* prompt = (const float*)d_in[1];
  const float* Wq     = (const float*)d_in[2];
  const float* Wk     = (const float*)d_in[3];
  const float* Wv     = (const float*)d_in[4];
  const float* Wproj  = (const float*)d_in[5];
  const float* Wg     = (const float*)d_in[6];
  const float* gamma  = (const float*)d_in[7];
  const float* beta   = (const float*)d_in[8];

  char* wsb = (char*)d_ws;
  u16* XY    = (u16*)(wsb + 0);           // [b][p'][512]: x | y
  u16* PT    = (u16*)(wsb + 33554432);    // prompt [b][p'][256]
  u16* QT    = (u16*)(wsb + 50331648);    // Q [b][p'][256]  (aliases Pd, GT)
  u16* KT    = (u16*)(wsb + 67108864);    // K [b][p'][256]  (aliases pS/pSS)
  u16* VT    = (u16*)(wsb + 83886080);    // V channel-major [b*256+c][4096]
  u16* OT    = (u16*)(wsb + 100663296);   // attn out [b][p'][256]
  u16* Wbf   = (u16*)(wsb + 117440512);   // Wq|Wk|Wv|Wproj|Wg bf16
  float* dx  = (float*)(wsb + 118226944);
  float* dp  = (float*)(wsb + 118751232);
  float* scl = (float*)(wsb + 119275520);
  float* shf = (float*)(wsb + 119276544);
  int* routed = (int*)(wsb + 119277568);
  float* Pd  = (float*)QT;                // 8MB, dead before qkv writes QT
  float* pS  = (float*)KT;                // 256KB, after attn (KT dead)
  float* pSS = (float*)(wsb + 67108864 + 262144);
  u16* GT = QT;                           // reuse: Q dead after attention

  wcvt_kernel<<<dim3(128, 5), 256, 0, stream>>>(Wq, Wk, Wv, Wproj, Wg, Wbf);
  pack_kernel<<<dim3(64, 16), 256, 0, stream>>>(x, prompt, XY, PT, Pd);
  dred_kernel<<<dim3(16, 8), 256, 0, stream>>>(Pd, dx, dp);
  route_kernel<<<B * NW, 64, 0, stream>>>(dx, dp, routed);
  qkv_kernel<<<dim3(256, 6), 256, 0, stream>>>(XY, PT, Wbf, QT, KT, VT);
  attn_kernel<<<B * NW, 512, 0, stream>>>(QT, KT, VT, routed, OT);
  proj_kernel<<<dim3(256, 2), 256, 0, stream>>>(OT, Wbf, XY);
  gate_kernel<<<dim3(256, 2), 256, 0, stream>>>(XY, Wbf, GT, pS, pSS);
  bnfin_kernel<<<1, 1024, 0, stream>>>(pS, pSS, gamma, beta, scl, shf);
  final_kernel<<<dim3(64, 8), 256, 0, stream>>>(x, XY, GT, scl, shf, (float*)d_out);
}

// Round 5
// 169.742 us; speedup vs baseline: 7.7431x; 1.1093x over previous
//
#include <hip/hip_runtime.h>
#include <math.h>

#define B 8
#define Cc 256
#define P 4096
#define NW 64
#define NH 8
#define HD 32
#define TOPK 4
#define SCALE 0.17677669529663687f

typedef unsigned short u16;
typedef __attribute__((ext_vector_type(4))) float f32x4;
typedef __attribute__((ext_vector_type(8))) short s16x8;
typedef __attribute__((ext_vector_type(4))) unsigned short u16x4;

#define MFMA(a, b, c) __builtin_amdgcn_mfma_f32_16x16x32_bf16(a, b, c, 0, 0, 0)

__device__ inline u16 f2bf(float f) {
  unsigned u = __float_as_uint(f);
  return (u16)((u + 0x7fffu + ((u >> 16) & 1u)) >> 16);
}
__device__ inline float bf2f(u16 h) { return __uint_as_float(((unsigned)h) << 16); }

// ---------------------------------------------------------------------------
// weights f32 -> bf16, all five in one launch (blockIdx.y = job)
// ---------------------------------------------------------------------------
__global__ __launch_bounds__(256) void wcvt_kernel(
    const float* __restrict__ Wq, const float* __restrict__ Wk,
    const float* __restrict__ Wv, const float* __restrict__ Wproj,
    const float* __restrict__ Wg, u16* __restrict__ Wbf) {
  int job = blockIdx.y;
  const float* src;
  u16* dst;
  int n;
  switch (job) {
    case 0: src = Wq;    dst = Wbf;          n = 65536;  break;
    case 1: src = Wk;    dst = Wbf + 65536;  n = 65536;  break;
    case 2: src = Wv;    dst = Wbf + 131072; n = 65536;  break;
    case 3: src = Wproj; dst = Wbf + 196608; n = 65536;  break;
    default: src = Wg;   dst = Wbf + 262144; n = 131072; break;
  }
  int i = (blockIdx.x * 256 + threadIdx.x) * 4;
  if (i < n) {
    float4 v = *(const float4*)(src + i);
    u16x4 o = {f2bf(v.x), f2bf(v.y), f2bf(v.z), f2bf(v.w)};
    *(u16x4*)(dst + i) = o;
  }
}

// ---------------------------------------------------------------------------
// pack v2: image f32 [b][c][64x64] -> windowed token-major bf16 + f32 window
// partial sums. Vectorized float4 loads; LDS transpose [c][px] pitch 68 with
// XOR swizzle pos = px0 ^ (((c>>3)&3)<<2)  (read phase ~conflict-free).
// ---------------------------------------------------------------------------
__global__ __launch_bounds__(256) void pack_kernel(
    const float* __restrict__ x, const float* __restrict__ prompt,
    u16* __restrict__ XY, u16* __restrict__ PT, float* __restrict__ Pd) {
  __shared__ u16 ldsd[256 * 68];
  __shared__ float pdl[256 * 9];   // [c][wx], pitch 9
  int y = blockIdx.x;
  int sb = blockIdx.y;
  int sel = sb >> 3, b = sb & 7;
  const float* src = (sel ? prompt : x) + (size_t)(b * 256) * 4096 + y * 64;
  int tid = threadIdx.x;
  int pxg = tid & 15;
  int tq = (tid >> 4) & 3;
  int wv = tid >> 6;
  int px0 = pxg * 4;
#pragma unroll
  for (int iter = 0; iter < 16; ++iter) {
    int c = wv * 64 + tq * 16 + iter;
    float4 v = *(const float4*)(src + (size_t)c * 4096 + px0);
    u16x4 o = {f2bf(v.x), f2bf(v.y), f2bf(v.z), f2bf(v.w)};
    int sw = ((c >> 3) & 3) << 2;
    *(u16x4*)(ldsd + c * 68 + (px0 ^ sw)) = o;
    // window-x partial sums, same summation tree as before (bit-identical)
    float s4 = v.x + v.y;
    s4 += v.z;
    s4 += v.w;
    // rebuild exact pairwise tree: ((p0+p1)+(p2+p3)) within float4
    s4 = (v.x + v.y) + (v.z + v.w);
    float s8 = s4 + __shfl_xor(s4, 1);
    if ((pxg & 1) == 0) pdl[c * 9 + (pxg >> 1)] = s8;
  }
  __syncthreads();
  // phase 2: token-major bf16 store (transpose read, swizzled -> ~2-way)
  int tok = tid >> 2, cgroup = tid & 3;
  int n = ((y >> 3) << 3) + (tok >> 3);
  int tk = ((y & 7) << 3) + (tok & 7);
  size_t prow = (size_t)b * 4096 + n * 64 + tk;
  u16* dst = sel ? (PT + prow * 256) : (XY + prow * 512);
#pragma unroll
  for (int cc = 0; cc < 8; ++cc) {
    int cb = cgroup * 8 + cc * 32;
    s16x8 v;
#pragma unroll
    for (int j = 0; j < 8; ++j) {
      int c = cb + j;
      int sw = ((c >> 3) & 3) << 2;
      v[j] = (short)ldsd[c * 68 + (tok ^ sw)];
    }
    *(s16x8*)(dst + cb) = v;
  }
  // phase 3: coalesced desc-partial store; Pd[(y*8+wx)*256 + c]
  float* pd = Pd + ((size_t)sb * 64 + y) * 2048;
#pragma unroll
  for (int i = 0; i < 8; ++i) {
    int idx = i * 256 + tid;
    int wx = idx >> 8, c = idx & 255;
    pd[idx] = pdl[c * 9 + wx];
  }
}

// ---------------------------------------------------------------------------
// reduce partials -> descriptors [b][c][n] (f32, deterministic order)
// ---------------------------------------------------------------------------
__global__ __launch_bounds__(256) void dred_kernel(
    const float* __restrict__ Pd, float* __restrict__ dx, float* __restrict__ dp) {
  int sb = blockIdx.x;
  int sel = sb >> 3, b = sb & 7;
  int c = threadIdx.x;
  float* dst = (sel ? dp : dx) + ((size_t)b * 256 + c) * 64;
  const float* src = Pd + (size_t)sb * 64 * 2048;
#pragma unroll
  for (int nn = 0; nn < 8; ++nn) {
    int n = blockIdx.y * 8 + nn;
    int wy = n >> 3, wx = n & 7;
    float s = 0.f;
#pragma unroll
    for (int yl = 0; yl < 8; ++yl)
      s += src[((wy * 8 + yl) * 8 + wx) * 256 + c];
    dst[n] = s * (1.f / 64.f);
  }
}

// ---------------------------------------------------------------------------
// routing (f32, exact)
// ---------------------------------------------------------------------------
__global__ __launch_bounds__(64) void route_kernel(
    const float* __restrict__ dx, const float* __restrict__ dp,
    int* __restrict__ routed) {
  int bq = blockIdx.x;
  int b = bq >> 6;
  int q = bq & 63;
  int lane = threadIdx.x;
  const float* dxb = dx + (size_t)b * Cc * NW;
  const float* dpb = dp + (size_t)b * Cc * NW;
  float s = 0.f;
  for (int c = 0; c < Cc; ++c)
    s = fmaf(dxb[c * NW + q], dpb[c * NW + lane], s);
  s *= (1.f / 16.f);
  for (int kk = 0; kk < TOPK; ++kk) {
    float v = s;
    int i = lane;
    for (int off = 32; off; off >>= 1) {
      float ov = __shfl_xor(v, off);
      int oi = __shfl_xor(i, off);
      if (ov > v || (ov == v && oi < i)) { v = ov; i = oi; }
    }
    if (lane == 0) routed[bq * TOPK + kk] = i;
    if (lane == i) s = -INFINITY;
  }
}

// ---------------------------------------------------------------------------
// shared MFMA GEMM core: acc += A[m0..+128][k] * W[n0..+128][k]
// ---------------------------------------------------------------------------
__device__ __forceinline__ void gemm_core(
    const u16* __restrict__ A, int lda, const u16* __restrict__ W, int K,
    int m0, int n0, int tid, u16* Asm, u16* Wsm, f32x4 (&acc)[4][4]) {
  int l = tid & 63, wv = tid >> 6;
  int lq = l & 15, g = l >> 4;
  int wm = (wv & 1) * 64, wn = (wv >> 1) * 64;
  for (int k0 = 0; k0 < K; k0 += 64) {
    s16x8 av[4], wvv[4];
#pragma unroll
    for (int i = 0; i < 4; ++i) {
      int s = i * 256 + tid, row = s >> 3, u = s & 7;
      av[i] = *(const s16x8*)(A + (size_t)(m0 + row) * lda + k0 + u * 8);
      wvv[i] = *(const s16x8*)(W + (size_t)(n0 + row) * K + k0 + u * 8);
    }
    __syncthreads();
#pragma unroll
    for (int i = 0; i < 4; ++i) {
      int s = i * 256 + tid, row = s >> 3, u = s & 7;
      int gu = u ^ (row & 7);
      *(s16x8*)(Asm + row * 64 + gu * 8) = av[i];
      *(s16x8*)(Wsm + row * 64 + gu * 8) = wvv[i];
    }
    __syncthreads();
#pragma unroll
    for (int ks = 0; ks < 2; ++ks) {
      s16x8 af[4], bfr[4];
#pragma unroll
      for (int mi = 0; mi < 4; ++mi) {
        int r = wm + 16 * mi + lq;
        af[mi] = *(const s16x8*)(Asm + r * 64 + ((4 * ks + g) ^ (r & 7)) * 8);
      }
#pragma unroll
      for (int ni = 0; ni < 4; ++ni) {
        int r = wn + 16 * ni + lq;
        bfr[ni] = *(const s16x8*)(Wsm + r * 64 + ((4 * ks + g) ^ (r & 7)) * 8);
      }
#pragma unroll
      for (int mi = 0; mi < 4; ++mi)
#pragma unroll
        for (int ni = 0; ni < 4; ++ni)
          acc[mi][ni] = MFMA(af[mi], bfr[ni], acc[mi][ni]);
    }
  }
}

__device__ __forceinline__ void store_rowmajor(
    f32x4 (&acc)[4][4], u16* __restrict__ Out, int ldo,
    size_t mbase, int nbase, int lq, int g) {
#pragma unroll
  for (int mi = 0; mi < 4; ++mi) {
    size_t mrow = mbase + 16 * mi + 4 * g;
#pragma unroll
    for (int r = 0; r < 4; ++r) {
      u16* orow = Out + (mrow + r) * ldo + nbase + lq;
#pragma unroll
      for (int ni = 0; ni < 4; ++ni)
        orow[16 * ni] = f2bf(acc[mi][ni][r]);
    }
  }
}

__device__ __forceinline__ void store_chanmajor(
    f32x4 (&acc)[4][4], u16* __restrict__ Out,
    int bb, int tb, int cbase, int lq) {
#pragma unroll
  for (int ni = 0; ni < 4; ++ni) {
    u16* ocol = Out + ((size_t)(bb * 256) + cbase + 16 * ni + lq) * 4096 + tb;
#pragma unroll
    for (int mi = 0; mi < 4; ++mi) {
      u16x4 pk = {f2bf(acc[mi][ni][0]), f2bf(acc[mi][ni][1]),
                  f2bf(acc[mi][ni][2]), f2bf(acc[mi][ni][3])};
      *(u16x4*)(ocol + 16 * mi) = pk;
    }
  }
}

// ---------------------------------------------------------------------------
// Q/K/V in one launch: jy<2 -> Q (A=x part of XY); jy 2..5 -> K|V (A=PT)
// ---------------------------------------------------------------------------
__global__ __launch_bounds__(256) void qkv_kernel(
    const u16* __restrict__ XY, const u16* __restrict__ PT,
    const u16* __restrict__ Wbf, u16* __restrict__ QT,
    u16* __restrict__ KT, u16* __restrict__ VT) {
  __shared__ u16 Asm[8192], Wsm[8192];
  int jy = blockIdx.y, m0 = blockIdx.x * 128;
  int tid = threadIdx.x;
  int l = tid & 63, wv = tid >> 6;
  int lq = l & 15, g = l >> 4;
  int wm = (wv & 1) * 64, wn = (wv >> 1) * 64;
  f32x4 acc[4][4];
#pragma unroll
  for (int mi = 0; mi < 4; ++mi)
#pragma unroll
    for (int ni = 0; ni < 4; ++ni)
      acc[mi][ni] = (f32x4){0.f, 0.f, 0.f, 0.f};

  const u16* A;
  const u16* W;
  int lda, n0;
  if (jy < 2) { A = XY; lda = 512; W = Wbf; n0 = jy * 128; }
  else        { A = PT; lda = 256; W = Wbf + 65536; n0 = (jy - 2) * 128; }
  gemm_core(A, lda, W, 256, m0, n0, tid, Asm, Wsm, acc);

  if (jy < 2) {
    store_rowmajor(acc, QT, 256, (size_t)(m0 + wm), n0 + wn, lq, g);
  } else if (n0 < 256) {
    store_rowmajor(acc, KT, 256, (size_t)(m0 + wm), n0 + wn, lq, g);
  } else {
    store_chanmajor(acc, VT, m0 >> 12, (m0 & 4095) + wm + 4 * g,
                    (n0 - 256) + wn, lq);
  }
}

// ---------------------------------------------------------------------------
// proj: y = Wproj * o  (A=OT), stores into XY cols 256..511
// ---------------------------------------------------------------------------
__global__ __launch_bounds__(256) void proj_kernel(
    const u16* __restrict__ OT, const u16* __restrict__ Wbf,
    u16* __restrict__ XY) {
  __shared__ u16 Asm[8192], Wsm[8192];
  int m0 = blockIdx.x * 128, n0 = blockIdx.y * 128;
  int tid = threadIdx.x;
  int l = tid & 63, wv = tid >> 6;
  int lq = l & 15, g = l >> 4;
  int wm = (wv & 1) * 64, wn = (wv >> 1) * 64;
  f32x4 acc[4][4];
#pragma unroll
  for (int mi = 0; mi < 4; ++mi)
#pragma unroll
    for (int ni = 0; ni < 4; ++ni)
      acc[mi][ni] = (f32x4){0.f, 0.f, 0.f, 0.f};
  gemm_core(OT, 256, Wbf + 196608, 256, m0, n0, tid, Asm, Wsm, acc);
  store_rowmajor(acc, XY + 256, 512, (size_t)(m0 + wm), n0 + wn, lq, g);
}

// ---------------------------------------------------------------------------
// gate: G = Wg * [x|y] (A=XY, K=512) + BN partial sums from f32 acc
// ---------------------------------------------------------------------------
__global__ __launch_bounds__(256) void gate_kernel(
    const u16* __restrict__ XY, const u16* __restrict__ Wbf,
    u16* __restrict__ GT, float* __restrict__ pS, float* __restrict__ pSS) {
  __shared__ u16 Asm[8192], Wsm[8192];
  int m0 = blockIdx.x * 128, n0 = blockIdx.y * 128;
  int tid = threadIdx.x;
  int l = tid & 63, wv = tid >> 6;
  int lq = l & 15, g = l >> 4;
  int wm = (wv & 1) * 64, wn = (wv >> 1) * 64;
  f32x4 acc[4][4];
#pragma unroll
  for (int mi = 0; mi < 4; ++mi)
#pragma unroll
    for (int ni = 0; ni < 4; ++ni)
      acc[mi][ni] = (f32x4){0.f, 0.f, 0.f, 0.f};
  gemm_core(XY, 512, Wbf + 262144, 512, m0, n0, tid, Asm, Wsm, acc);
  store_rowmajor(acc, GT, 256, (size_t)(m0 + wm), n0 + wn, lq, g);

  // BN partials over this block's 128 rows
  float cs[4], cq[4];
#pragma unroll
  for (int ni = 0; ni < 4; ++ni) {
    float s = 0.f, q2 = 0.f;
#pragma unroll
    for (int mi = 0; mi < 4; ++mi)
#pragma unroll
      for (int r = 0; r < 4; ++r) {
        float v = acc[mi][ni][r];
        s += v;
        q2 = fmaf(v, v, q2);
      }
    cs[ni] = s;
    cq[ni] = q2;
  }
#pragma unroll
  for (int ni = 0; ni < 4; ++ni) {
    cs[ni] += __shfl_xor(cs[ni], 16);
    cs[ni] += __shfl_xor(cs[ni], 32);
    cq[ni] += __shfl_xor(cq[ni], 16);
    cq[ni] += __shfl_xor(cq[ni], 32);
  }
  float* sS = (float*)Asm;
  float* sQ = sS + 128;
  __syncthreads();
  if ((wv & 1) == 0 && g == 0) {
#pragma unroll
    for (int ni = 0; ni < 4; ++ni) {
      int col = wn + 16 * ni + lq;
      sS[col] = cs[ni];
      sQ[col] = cq[ni];
    }
  }
  __syncthreads();
  if ((wv & 1) == 1 && g == 0) {
#pragma unroll
    for (int ni = 0; ni < 4; ++ni) {
      int col = wn + 16 * ni + lq;
      sS[col] += cs[ni];
      sQ[col] += cq[ni];
    }
  }
  __syncthreads();
  if (tid < 128) {
    pS[(size_t)blockIdx.x * 256 + n0 + tid] = sS[tid];
    pSS[(size_t)blockIdx.x * 256 + n0 + tid] = sQ[tid];
  }
}

// ---------------------------------------------------------------------------
// MFMA attention (unchanged)
// ---------------------------------------------------------------------------
__global__ __launch_bounds__(512) void attn_kernel(
    const u16* __restrict__ Qb, const u16* __restrict__ Kb,
    const u16* __restrict__ Vt, const int* __restrict__ routed,
    u16* __restrict__ Ob) {
  __shared__ u16 Plds[8 * 4096];
  int bn = blockIdx.x, b = bn >> 6, n = bn & 63;
  int h = threadIdx.x >> 6, l = threadIdx.x & 63;
  int lq = l & 15, g = l >> 4;
  char* Pw = (char*)(Plds + h * 4096);

  const u16* Qrow = Qb + ((size_t)(b * 4096) + n * 64) * 256 + h * 32 + g * 8;
  s16x8 qf[4];
#pragma unroll
  for (int qi = 0; qi < 4; ++qi)
    qf[qi] = *(const s16x8*)(Qrow + (16 * qi + lq) * 256);

  f32x4 acc[4][2];
#pragma unroll
  for (int qi = 0; qi < 4; ++qi) {
    acc[qi][0] = (f32x4){0.f, 0.f, 0.f, 0.f};
    acc[qi][1] = (f32x4){0.f, 0.f, 0.f, 0.f};
  }
  float denom[4] = {0.f, 0.f, 0.f, 0.f};
  const f32x4 zero4 = {0.f, 0.f, 0.f, 0.f};
  const int* rptr = routed + bn * TOPK;

  for (int kk = 0; kk < TOPK; ++kk) {
    int pw = __builtin_amdgcn_readfirstlane(rptr[kk]);
    const u16* Krow = Kb + ((size_t)(b * 4096) + pw * 64) * 256 + h * 32 + g * 8;
    const u16* Vrow = Vt + ((size_t)(b * 256) + h * 32 + lq) * 4096 + pw * 64 + 8 * g;
#pragma unroll
    for (int kvi = 0; kvi < 4; ++kvi) {
      s16x8 kf = *(const s16x8*)(Krow + (16 * kvi + lq) * 256);
      f32x4 sv[4];
#pragma unroll
      for (int qi = 0; qi < 4; ++qi)
        sv[qi] = MFMA(kf, qf[qi], zero4);
#pragma unroll
      for (int qi = 0; qi < 4; ++qi) {
        float p0 = __expf(sv[qi][0] * SCALE);
        float p1 = __expf(sv[qi][1] * SCALE);
        float p2 = __expf(sv[qi][2] * SCALE);
        float p3 = __expf(sv[qi][3] * SCALE);
        denom[qi] += (p0 + p1) + (p2 + p3);
        uint2 pk;
        pk.x = (unsigned)f2bf(p0) | ((unsigned)f2bf(p1) << 16);
        pk.y = (unsigned)f2bf(p2) | ((unsigned)f2bf(p3) << 16);
        int q = 16 * qi + lq;
        int kvb = (16 * kvi + 4 * g) * 2;
        *(uint2*)(Pw + q * 128 + (kvb ^ ((q & 7) << 4))) = pk;
      }
    }
#pragma unroll
    for (int s = 0; s < 2; ++s) {
      s16x8 vf[2];
#pragma unroll
      for (int di = 0; di < 2; ++di)
        vf[di] = *(const s16x8*)(Vrow + (size_t)(16 * di) * 4096 + 32 * s);
#pragma unroll
      for (int qi = 0; qi < 4; ++qi) {
        int q = 16 * qi + lq;
        s16x8 pf = *(const s16x8*)(Pw + q * 128 +
                                   ((64 * s + 16 * g) ^ ((q & 7) << 4)));
#pragma unroll
        for (int di = 0; di < 2; ++di)
          acc[qi][di] = MFMA(pf, vf[di], acc[qi][di]);
      }
    }
  }

#pragma unroll
  for (int qi = 0; qi < 4; ++qi) {
    denom[qi] += __shfl_xor(denom[qi], 16);
    denom[qi] += __shfl_xor(denom[qi], 32);
  }
  u16* Orow = Ob + ((size_t)(b * 4096) + n * 64) * 256 + h * 32;
#pragma unroll
  for (int qi = 0; qi < 4; ++qi) {
    float inv = 1.f / denom[qi];
#pragma unroll
    for (int r = 0; r < 4; ++r) {
      float nr = __shfl(inv, 4 * g + r);
#pragma unroll
      for (int di = 0; di < 2; ++di)
        Orow[(16 * qi + 4 * g + r) * 256 + 16 * di + lq] =
            f2bf(acc[qi][di][r] * nr);
    }
  }
}

// ---------------------------------------------------------------------------
// BN finalize: sum 256 block-partials per channel -> scale/shift
// ---------------------------------------------------------------------------
__global__ __launch_bounds__(1024) void bnfin_kernel(
    const float* __restrict__ pS, const float* __restrict__ pSS,
    const float* __restrict__ gamma, const float* __restrict__ beta,
    float* __restrict__ scale, float* __restrict__ shift) {
  int tid = threadIdx.x;
  int c = tid >> 2, part = tid & 3;
  float S = 0.f, SS = 0.f;
  for (int m = part * 64; m < part * 64 + 64; ++m) {
    S += pS[m * 256 + c];
    SS += pSS[m * 256 + c];
  }
  __shared__ float rS[4][256], rQ[4][256];
  rS[part][c] = S;
  rQ[part][c] = SS;
  __syncthreads();
  if (tid < 256) {
    int cc = tid;
    float S2 = rS[0][cc] + rS[1][cc] + rS[2][cc] + rS[3][cc];
    float Q2 = rQ[0][cc] + rQ[1][cc] + rQ[2][cc] + rQ[3][cc];
    const float invN = 1.f / 32768.f;
    float mean = S2 * invN;
    float var = Q2 * invN - mean * mean;
    float sc = rsqrtf(var + 1e-5f) * gamma[cc];
    scale[cc] = sc;
    shift[cc] = beta[cc] - mean * sc;
  }
}

// ---------------------------------------------------------------------------
// final: block = (image row y, b). LDS-stage Y,G (token-major) with chunk
// XOR swizzle; compute phase lane = pixel -> fully coalesced x/out.
// ---------------------------------------------------------------------------
__global__ __launch_bounds__(256) void final_kernel(
    const float* __restrict__ x, const u16* __restrict__ XY,
    const u16* __restrict__ GT, const float* __restrict__ scale,
    const float* __restrict__ shift, float* __restrict__ out) {
  __shared__ u16 Yl[64 * 256];
  __shared__ u16 Gl[64 * 256];
  __shared__ float sSc[256], sSh[256];
  int y = blockIdx.x, b = blockIdx.y;
  int tid = threadIdx.x;
  sSc[tid] = scale[tid];
  sSh[tid] = shift[tid];
  {
    int r = tid >> 2;
    int n = ((y >> 3) << 3) + (r >> 3);
    int t = ((y & 7) << 3) + (r & 7);
    size_t prow = (size_t)b * 4096 + n * 64 + t;
    const u16* ysrc = XY + prow * 512 + 256;
    const u16* gsrc = GT + prow * 256;
#pragma unroll
    for (int cc = 0; cc < 8; ++cc) {
      int chunk = (tid & 3) * 8 + cc;
      int off = r * 256 + ((chunk ^ (r & 31)) << 3);
      *(s16x8*)(Yl + off) = *(const s16x8*)(ysrc + chunk * 8);
      *(s16x8*)(Gl + off) = *(const s16x8*)(gsrc + chunk * 8);
    }
  }
  __syncthreads();
  int lane = tid & 63, wq = tid >> 6;
  size_t base = (size_t)(b * 256) * 4096 + y * 64 + lane;
#pragma unroll 2
  for (int ch = 0; ch < 8; ++ch) {
    int chunk = wq * 8 + ch;
    int off = lane * 256 + ((chunk ^ (lane & 31)) << 3);
    s16x8 yv = *(const s16x8*)(Yl + off);
    s16x8 gv = *(const s16x8*)(Gl + off);
#pragma unroll
    for (int j = 0; j < 8; ++j) {
      int c = chunk * 8 + j;
      size_t a = base + (size_t)c * 4096;
      float gate = 1.f / (1.f + __expf(-fmaf(bf2f((u16)gv[j]), sSc[c], sSh[c])));
      out[a] = x[a] + gate * bf2f((u16)yv[j]);
    }
  }
}

// ---------------------------------------------------------------------------
extern "C" void kernel_launch(void* const* d_in, const int* in_sizes, int n_in,
                              void* d_out, int out_size, void* d_ws, size_t ws_size,
                              hipStream_t stream) {
  const float* x      = (const float*)d_in[0];
  const float* prompt = (const float*)d_in[1];
  const float* Wq     = (const float*)d_in[2];
  const float* Wk     = (const float*)d_in[3];
  const float* Wv     = (const float*)d_in[4];
  const float* Wproj  = (const float*)d_in[5];
  const float* Wg     = (const float*)d_in[6];
  const float* gamma  = (const float*)d_in[7];
  const float* beta   = (const float*)d_in[8];

  char* wsb = (char*)d_ws;
  u16* XY    = (u16*)(wsb + 0);           // [b][p'][512]: x | y
  u16* PT    = (u16*)(wsb + 33554432);    // prompt [b][p'][256]
  u16* QT    = (u16*)(wsb + 50331648);    // Q [b][p'][256]  (aliases Pd, GT)
  u16* KT    = (u16*)(wsb + 67108864);    // K [b][p'][256]  (aliases pS/pSS)
  u16* VT    = (u16*)(wsb + 83886080);    // V channel-major [b*256+c][4096]
  u16* OT    = (u16*)(wsb + 100663296);   // attn out [b][p'][256]
  u16* Wbf   = (u16*)(wsb + 117440512);   // Wq|Wk|Wv|Wproj|Wg bf16
  float* dx  = (float*)(wsb + 118226944);
  float* dp  = (float*)(wsb + 118751232);
  float* scl = (float*)(wsb + 119275520);
  float* shf = (float*)(wsb + 119276544);
  int* routed = (int*)(wsb + 119277568);
  float* Pd  = (float*)QT;                // 8MB, dead before qkv writes QT
  float* pS  = (float*)KT;                // 256KB, after attn (KT dead)
  float* pSS = (float*)(wsb + 67108864 + 262144);
  u16* GT = QT;                           // reuse: Q dead after attention

  wcvt_kernel<<<dim3(128, 5), 256, 0, stream>>>(Wq, Wk, Wv, Wproj, Wg, Wbf);
  pack_kernel<<<dim3(64, 16), 256, 0, stream>>>(x, prompt, XY, PT, Pd);
  dred_kernel<<<dim3(16, 8), 256, 0, stream>>>(Pd, dx, dp);
  route_kernel<<<B * NW, 64, 0, stream>>>(dx, dp, routed);
  qkv_kernel<<<dim3(256, 6), 256, 0, stream>>>(XY, PT, Wbf, QT, KT, VT);
  attn_kernel<<<B * NW, 512, 0, stream>>>(QT, KT, VT, routed, OT);
  proj_kernel<<<dim3(256, 2), 256, 0, stream>>>(OT, Wbf, XY);
  gate_kernel<<<dim3(256, 2), 256, 0, stream>>>(XY, Wbf, GT, pS, pSS);
  bnfin_kernel<<<1, 1024, 0, stream>>>(pS, pSS, gamma, beta, scl, shf);
  final_kernel<<<dim3(64, 8), 256, 0, stream>>>(x, XY, GT, scl, shf, (float*)d_out);
}